// Round 1
// baseline (761.108 us; speedup 1.0000x reference)
//
#include <hip/hip_runtime.h>

typedef unsigned short u16;
typedef unsigned int   u32;
typedef __bf16 bf16x8 __attribute__((ext_vector_type(8)));
typedef float  f32x4  __attribute__((ext_vector_type(4)));
typedef u16    u16x4  __attribute__((ext_vector_type(4)));
typedef u16    u16x8  __attribute__((ext_vector_type(8)));

// ---------- helpers ----------
__device__ __forceinline__ u16 f2bf(float f) {
  u32 u = __float_as_uint(f);
  u32 r = u + 0x7fffu + ((u >> 16) & 1u);   // RTNE
  return (u16)(r >> 16);
}

__device__ __forceinline__ void gl16(const void* g, void* l) {
  __builtin_amdgcn_global_load_lds((__attribute__((address_space(1))) void*)(g),
                                   (__attribute__((address_space(3))) void*)(l),
                                   16, 0, 0);
}

// ---------- fp32 -> bf16 elementwise (layout preserving) ----------
__global__ __launch_bounds__(256) void cvt_f32_bf16(const float* __restrict__ x,
                                                    u16* __restrict__ y, int n4) {
  for (int i = blockIdx.x * 256 + threadIdx.x; i < n4; i += gridDim.x * 256) {
    float4 v = ((const float4*)x)[i];
    u16x4 o;
    o[0] = f2bf(v.x); o[1] = f2bf(v.y); o[2] = f2bf(v.z); o[3] = f2bf(v.w);
    ((u16x4*)y)[i] = o;
  }
}

// ---------- transpose+convert: W[K][N] fp32 -> Wt[Npad][K] bf16 (pad rows zero) ----------
__global__ __launch_bounds__(256) void transpose_w(const float* __restrict__ W,
                                                   u16* __restrict__ Wt,
                                                   int K, int N, int Npad) {
  __shared__ float tile[32][33];
  const int n0 = blockIdx.x * 32, k0 = blockIdx.y * 32;
  const int tid = threadIdx.x;
  const int r  = tid >> 3;          // 0..31
  const int c4 = (tid & 7) << 2;    // 0,4,..,28
  float4 v = make_float4(0.f, 0.f, 0.f, 0.f);
  if (n0 + c4 < N) v = *(const float4*)(W + (size_t)(k0 + r) * N + n0 + c4);
  tile[r][c4 + 0] = v.x; tile[r][c4 + 1] = v.y;
  tile[r][c4 + 2] = v.z; tile[r][c4 + 3] = v.w;
  __syncthreads();
  u16x4 o;
  o[0] = f2bf(tile[c4 + 0][r]); o[1] = f2bf(tile[c4 + 1][r]);
  o[2] = f2bf(tile[c4 + 2][r]); o[3] = f2bf(tile[c4 + 3][r]);
  *(u16x4*)(Wt + (size_t)(n0 + r) * K + k0 + c4) = o;
}

// ---------- GEMM: C[M][N] f32 = A[M][K] bf16 * Bt[N][K]^T bf16 ----------
__global__ __launch_bounds__(256) void gemm_bt(const u16* __restrict__ A,
                                               const u16* __restrict__ Bt,
                                               float* __restrict__ C,
                                               int M, int N, int K) {
  __shared__ u16 As[128 * 64];
  __shared__ u16 Bs[128 * 64];
  const int tid = threadIdx.x;
  const int lane = tid & 63, w = tid >> 6;
  const int n0 = blockIdx.x << 7, m0 = blockIdx.y << 7;
  const int wr = w >> 1, wc = w & 1;
  const int lr = lane & 15, lg = lane >> 4;
  f32x4 acc[4][4] = {};
  const int nkt = K >> 6;
  const char* Ab = (const char*)A;
  const char* Bb = (const char*)Bt;
  const int stageOff = (w << 10) + (lane << 4);
  for (int kt = 0; kt < nkt; ++kt) {
    __syncthreads();
    const size_t kb = (size_t)kt << 7;   // byte offset of k-tile within a row
    #pragma unroll
    for (int o = 0; o < 16384; o += 4096) {
      int ofs = stageOff + o;
      int row = ofs >> 7;
      int cb  = ofs & 127;
      gl16(Ab + (size_t)(m0 + row) * K * 2 + kb + cb, (char*)As + ofs);
      gl16(Bb + (size_t)(n0 + row) * K * 2 + kb + cb, (char*)Bs + ofs);
    }
    __syncthreads();
    bf16x8 a[4][2], b[4][2];
    #pragma unroll
    for (int m = 0; m < 4; ++m)
      #pragma unroll
      for (int kf = 0; kf < 2; ++kf)
        a[m][kf] = *(const bf16x8*)(As + ((wr * 64 + m * 16 + lr) * 64 + kf * 32 + lg * 8));
    #pragma unroll
    for (int n = 0; n < 4; ++n)
      #pragma unroll
      for (int kf = 0; kf < 2; ++kf)
        b[n][kf] = *(const bf16x8*)(Bs + ((wc * 64 + n * 16 + lr) * 64 + kf * 32 + lg * 8));
    #pragma unroll
    for (int kf = 0; kf < 2; ++kf)
      #pragma unroll
      for (int m = 0; m < 4; ++m)
        #pragma unroll
        for (int n = 0; n < 4; ++n)
          acc[m][n] = __builtin_amdgcn_mfma_f32_16x16x32_bf16(a[m][kf], b[n][kf], acc[m][n], 0, 0, 0);
  }
  #pragma unroll
  for (int m = 0; m < 4; ++m) {
    const int row0 = m0 + wr * 64 + m * 16 + lg * 4;
    #pragma unroll
    for (int n = 0; n < 4; ++n) {
      const int col = n0 + wc * 64 + n * 16 + lr;
      #pragma unroll
      for (int r = 0; r < 4; ++r)
        C[(size_t)(row0 + r) * N + col] = acc[m][n][r];
    }
  }
}

// ---------- RMSNorm for q_c: x[2048][1536] f32 -> y bf16 ----------
__global__ __launch_bounds__(256) void norm_q_kernel(const float* __restrict__ x,
                                                     const float* __restrict__ w,
                                                     u16* __restrict__ y) {
  const int row = blockIdx.x, tid = threadIdx.x;
  const float* xr = x + (size_t)row * 1536;
  float v[6]; float ss = 0.f;
  #pragma unroll
  for (int i = 0; i < 6; ++i) { v[i] = xr[tid + i * 256]; ss += v[i] * v[i]; }
  __shared__ float sm[4];
  #pragma unroll
  for (int o = 32; o > 0; o >>= 1) ss += __shfl_down(ss, o, 64);
  if ((tid & 63) == 0) sm[tid >> 6] = ss;
  __syncthreads();
  float tot = sm[0] + sm[1] + sm[2] + sm[3];
  float rs = rsqrtf(tot * (1.f / 1536.f) + 1e-6f);
  #pragma unroll
  for (int i = 0; i < 6; ++i)
    y[(size_t)row * 1536 + tid + i * 256] = f2bf(v[i] * rs * w[tid + i * 256]);
}

// ---------- RMSNorm for compressed kv + RoPE(k_rope) ----------
__global__ __launch_bounds__(256) void norm_kv_kernel(const float* __restrict__ kva, // [2048][640]
                                                      const float* __restrict__ w,
                                                      const int* __restrict__ pos,
                                                      u16* __restrict__ comp,   // [2048][512]
                                                      u16* __restrict__ krope)  // [2048][64]
{
  const int row = blockIdx.x, tid = threadIdx.x;
  const float* xr = kva + (size_t)row * 640;
  float v0 = xr[tid], v1 = xr[tid + 256];
  float ss = v0 * v0 + v1 * v1;
  __shared__ float sm[4];
  #pragma unroll
  for (int o = 32; o > 0; o >>= 1) ss += __shfl_down(ss, o, 64);
  if ((tid & 63) == 0) sm[tid >> 6] = ss;
  __syncthreads();
  float tot = sm[0] + sm[1] + sm[2] + sm[3];
  float rs = rsqrtf(tot * (1.f / 512.f) + 1e-6f);
  comp[(size_t)row * 512 + tid]       = f2bf(v0 * rs * w[tid]);
  comp[(size_t)row * 512 + tid + 256] = f2bf(v1 * rs * w[tid + 256]);
  if (tid < 32) {
    float p = (float)pos[row];
    float inv = powf(10000.0f, -(float)(2 * tid) * (1.0f / 64.0f));
    float ang = p * inv;
    float c = cosf(ang), s = sinf(ang);
    float x1 = xr[512 + 2 * tid], x2 = xr[512 + 2 * tid + 1];
    krope[(size_t)row * 64 + 2 * tid]     = f2bf(x1 * c - x2 * s);
    krope[(size_t)row * 64 + 2 * tid + 1] = f2bf(x1 * s + x2 * c);
  }
}

// ---------- RoPE(q) + relayout to q_all[h][t][192] bf16 ----------
__global__ __launch_bounds__(256) void rope_q_kernel(const float* __restrict__ qb, // [2048][6144]
                                                     const int* __restrict__ pos,
                                                     u16* __restrict__ q_all) {
  const int t = blockIdx.x, tid = threadIdx.x;
  const float* qr = qb + (size_t)t * 6144;
  const float p = (float)pos[t];
  for (int idx = tid; idx < 4096; idx += 256) {
    int h = idx >> 7, d = idx & 127;
    q_all[((size_t)h * 2048 + t) * 192 + d] = f2bf(qr[h * 192 + d]);
  }
  for (int idx = tid; idx < 1024; idx += 256) {
    int h = idx >> 5, i = idx & 31;
    float inv = powf(10000.0f, -(float)(2 * i) * (1.0f / 64.0f));
    float ang = p * inv;
    float c = cosf(ang), s = sinf(ang);
    float x1 = qr[h * 192 + 128 + 2 * i], x2 = qr[h * 192 + 128 + 2 * i + 1];
    size_t ob = ((size_t)h * 2048 + t) * 192 + 128;
    q_all[ob + 2 * i]     = f2bf(x1 * c - x2 * s);
    q_all[ob + 2 * i + 1] = f2bf(x1 * s + x2 * c);
  }
}

// ---------- split kv -> k_all[h][s][200] (nope|rope|pad), v_t[h][d][2048] ----------
__global__ __launch_bounds__(256) void kvsplit_kernel(const float* __restrict__ kv,   // [2048][8192]
                                                      const u16* __restrict__ krope, // [2048][64]
                                                      u16* __restrict__ k_all,
                                                      u16* __restrict__ v_t) {
  const int h = blockIdx.x & 31, st = blockIdx.x >> 5, tid = threadIdx.x;
  const int s0 = st * 64;
  for (int idx = tid; idx < 8192; idx += 256) {
    int s = idx >> 7, d = idx & 127;
    k_all[((size_t)h * 2048 + s0 + s) * 200 + d] =
        f2bf(kv[(size_t)(s0 + s) * 8192 + h * 256 + d]);
  }
  for (int idx = tid; idx < 4096; idx += 256) {
    int s = idx >> 6, j = idx & 63;
    k_all[((size_t)h * 2048 + s0 + s) * 200 + 128 + j] = krope[(size_t)(s0 + s) * 64 + j];
  }
  __shared__ u16 vs[64][128];
  for (int idx = tid; idx < 8192; idx += 256) {
    int s = idx >> 7, d = idx & 127;
    vs[s][d] = f2bf(kv[(size_t)(s0 + s) * 8192 + h * 256 + 128 + d]);
  }
  __syncthreads();
  const int d = tid >> 1, sh = (tid & 1) * 32;
  u16 tmp[32];
  #pragma unroll
  for (int i = 0; i < 32; ++i) tmp[i] = vs[sh + i][d];
  #pragma unroll
  for (int b = 0; b < 4; ++b) {
    u16x8 o;
    #pragma unroll
    for (int j = 0; j < 8; ++j) o[j] = tmp[b * 8 + j];
    *(u16x8*)(v_t + ((size_t)h * 128 + d) * 2048 + s0 + sh + b * 8) = o;
  }
}

// ---------- flash attention: per block (head, 64 q rows), causal ----------
#define ATT_SCALE 0.07216878364870323f   // 192^-0.5
__global__ __launch_bounds__(256) void attn_fwd(const u16* __restrict__ q_all,
                                                const u16* __restrict__ k_all,
                                                const u16* __restrict__ v_t,
                                                u16* __restrict__ attnb) {
  __shared__ u16 Kl[64 * 200];
  __shared__ u16 Vl[128 * 72];
  __shared__ u16 Pl[4][16 * 72];
  const int tid = threadIdx.x;
  const int lane = tid & 63, w = tid >> 6;
  const int h = blockIdx.x & 31, qt = blockIdx.x >> 5;
  const int lr = lane & 15, lg = lane >> 4;
  const int qrow = qt * 64 + w * 16 + lr;

  bf16x8 qf[6];
  const u16* qb = q_all + ((size_t)h * 2048 + qrow) * 192 + lg * 8;
  #pragma unroll
  for (int kf = 0; kf < 6; ++kf) qf[kf] = *(const bf16x8*)(qb + kf * 32);

  f32x4 O[8] = {};
  float mrow[4] = {-1e30f, -1e30f, -1e30f, -1e30f};
  float lrow[4] = {0.f, 0.f, 0.f, 0.f};
  const char* kh = (const char*)(k_all + (size_t)h * 2048 * 200);
  const char* vh = (const char*)(v_t + (size_t)h * 128 * 2048);
  const int ntile = qt + 1;
  const int stageOff = (w << 10) + (lane << 4);

  for (int st = 0; st < ntile; ++st) {
    const int s0 = st * 64;
    __syncthreads();
    {
      const char* src = kh + (size_t)s0 * 400;        // contiguous 25600B tile
      for (int o = stageOff; o < 25600; o += 4096)
        gl16(src + o, (char*)Kl + o);
    }
    for (int o = stageOff; o < 18432; o += 4096) {    // V tile, rows padded to 144B
      int row = o / 144;
      int rem = o - row * 144;
      const char* src = vh + (size_t)row * 4096 + (size_t)s0 * 2 + (rem < 128 ? rem : 0);
      gl16(src, (char*)Vl + o);
    }
    __syncthreads();

    f32x4 S[4];
    #pragma unroll
    for (int sb = 0; sb < 4; ++sb) {
      f32x4 a = {};
      #pragma unroll
      for (int kf = 0; kf < 6; ++kf) {
        bf16x8 bk = *(const bf16x8*)(Kl + (sb * 16 + lr) * 200 + kf * 32 + lg * 8);
        a = __builtin_amdgcn_mfma_f32_16x16x32_bf16(qf[kf], bk, a, 0, 0, 0);
      }
      S[sb] = a;
    }

    const int qg0 = qt * 64 + w * 16 + lg * 4;
    #pragma unroll
    for (int sb = 0; sb < 4; ++sb) {
      int sc = s0 + sb * 16 + lr;
      #pragma unroll
      for (int r = 0; r < 4; ++r) {
        float v = S[sb][r] * ATT_SCALE;
        S[sb][r] = (sc > qg0 + r) ? -1e30f : v;
      }
    }

    float tmax[4];
    #pragma unroll
    for (int r = 0; r < 4; ++r) {
      float t = fmaxf(fmaxf(S[0][r], S[1][r]), fmaxf(S[2][r], S[3][r]));
      #pragma unroll
      for (int o2 = 1; o2 < 16; o2 <<= 1) t = fmaxf(t, __shfl_xor(t, o2, 64));
      tmax[r] = t;
    }
    float alpha[4];
    #pragma unroll
    for (int r = 0; r < 4; ++r) {
      float mn = fmaxf(mrow[r], tmax[r]);
      alpha[r] = __expf(mrow[r] - mn);
      mrow[r] = mn;
    }
    float rsum[4] = {0.f, 0.f, 0.f, 0.f};
    #pragma unroll
    for (int sb = 0; sb < 4; ++sb)
      #pragma unroll
      for (int r = 0; r < 4; ++r) {
        float p = __expf(S[sb][r] - mrow[r]);
        S[sb][r] = p;
        rsum[r] += p;
      }
    #pragma unroll
    for (int r = 0; r < 4; ++r) {
      float t = rsum[r];
      #pragma unroll
      for (int o2 = 1; o2 < 16; o2 <<= 1) t += __shfl_xor(t, o2, 64);
      lrow[r] = lrow[r] * alpha[r] + t;
    }
    #pragma unroll
    for (int nb = 0; nb < 8; ++nb)
      #pragma unroll
      for (int r = 0; r < 4; ++r) O[nb][r] *= alpha[r];

    u16* pw = Pl[w];
    #pragma unroll
    for (int sb = 0; sb < 4; ++sb)
      #pragma unroll
      for (int r = 0; r < 4; ++r)
        pw[(lg * 4 + r) * 72 + sb * 16 + lr] = f2bf(S[sb][r]);

    #pragma unroll
    for (int k2 = 0; k2 < 2; ++k2) {
      bf16x8 ap = *(const bf16x8*)(pw + lr * 72 + k2 * 32 + lg * 8);
      #pragma unroll
      for (int nb = 0; nb < 8; ++nb) {
        bf16x8 bv = *(const bf16x8*)(Vl + (nb * 16 + lr) * 72 + k2 * 32 + lg * 8);
        O[nb] = __builtin_amdgcn_mfma_f32_16x16x32_bf16(ap, bv, O[nb], 0, 0, 0);
      }
    }
  }

  const int trow0 = qt * 64 + w * 16 + lg * 4;
  #pragma unroll
  for (int nb = 0; nb < 8; ++nb) {
    const int col = h * 128 + nb * 16 + lr;
    #pragma unroll
    for (int r = 0; r < 4; ++r)
      attnb[(size_t)(trow0 + r) * 4096 + col] = f2bf(O[nb][r] / lrow[r]);
  }
}

// ---------- host ----------
extern "C" void kernel_launch(void* const* d_in, const int* in_sizes, int n_in,
                              void* d_out, int out_size, void* d_ws, size_t ws_size,
                              hipStream_t stream) {
  const int*   positions = (const int*)d_in[0];
  const float* hidden    = (const float*)d_in[1];
  const float* w_q_a     = (const float*)d_in[2];
  const float* q_a_norm  = (const float*)d_in[3];
  const float* w_q_b     = (const float*)d_in[4];
  const float* w_kv_a    = (const float*)d_in[5];
  const float* kv_a_norm = (const float*)d_in[6];
  const float* w_kv_b    = (const float*)d_in[7];
  const float* w_o       = (const float*)d_in[8];
  float* out = (float*)d_out;
  char*  ws  = (char*)d_ws;

  // workspace layout (bytes) -- total 223,608,832
  u16* hs_bf  = (u16*)(ws + 0);                       // 20,971,520
  u16* Wt     = (u16*)(ws + 20971520);                // 41,943,040 region (reused)
  char* Creg  = ws + 62914560;                        // 67,108,864 region (reused)
  float* q_lin  = (float*)Creg;                       // 12,582,912
  float* kv_a   = (float*)(Creg + 12582912);          //  5,242,880
  float* q_big  = (float*)Creg;                       // 50,331,648 (after norms)
  float* kv_big = (float*)Creg;                       // 67,108,864 (after rope_q)
  u16* q_c_n  = (u16*)(ws + 130023424);               //  6,291,456
  u16* comp   = (u16*)(ws + 136314880);               //  2,097,152
  u16* krope  = (u16*)(ws + 138412032);               //    262,144
  u16* q_all  = (u16*)(ws + 138674176);               // 25,165,824
  u16* k_all  = (u16*)(ws + 163840000);               // 26,214,400
  u16* v_t    = (u16*)(ws + 190054400);               // 16,777,216
  u16* attnb  = (u16*)(ws + 206831616);               // 16,777,216

  u16* wqa_t  = Wt;
  u16* wkva_t = Wt + (size_t)1536 * 5120;

  // 1) conversions for the first stage
  cvt_f32_bf16<<<2048, 256, 0, stream>>>(hidden, hs_bf, (2048 * 5120) / 4);
  transpose_w<<<dim3(48, 160), 256, 0, stream>>>(w_q_a,  wqa_t,  5120, 1536, 1536);
  transpose_w<<<dim3(20, 160), 256, 0, stream>>>(w_kv_a, wkva_t, 5120, 576,  640);

  // 2) LoRA-A GEMMs
  gemm_bt<<<dim3(12, 16), 256, 0, stream>>>(hs_bf, wqa_t,  q_lin, 2048, 1536, 5120);
  gemm_bt<<<dim3(5, 16),  256, 0, stream>>>(hs_bf, wkva_t, kv_a,  2048, 640,  5120);

  // 3) norms (+ k rope)
  norm_q_kernel<<<2048, 256, 0, stream>>>(q_lin, q_a_norm, q_c_n);
  norm_kv_kernel<<<2048, 256, 0, stream>>>(kv_a, kv_a_norm, positions, comp, krope);

  // 4) q up-projection + rope + relayout
  transpose_w<<<dim3(192, 48), 256, 0, stream>>>(w_q_b, Wt, 1536, 6144, 6144);
  gemm_bt<<<dim3(48, 16), 256, 0, stream>>>(q_c_n, Wt, q_big, 2048, 6144, 1536);
  rope_q_kernel<<<2048, 256, 0, stream>>>(q_big, positions, q_all);

  // 5) kv up-projection + split/relayout
  transpose_w<<<dim3(256, 16), 256, 0, stream>>>(w_kv_b, Wt, 512, 8192, 8192);
  gemm_bt<<<dim3(64, 16), 256, 0, stream>>>(comp, Wt, kv_big, 2048, 8192, 512);
  kvsplit_kernel<<<1024, 256, 0, stream>>>(kv_big, krope, k_all, v_t);

  // 6) attention
  transpose_w<<<dim3(160, 128), 256, 0, stream>>>(w_o, Wt, 4096, 5120, 5120);
  attn_fwd<<<1024, 256, 0, stream>>>(q_all, k_all, v_t, attnb);

  // 7) output projection (fp32 out)
  gemm_bt<<<dim3(40, 16), 256, 0, stream>>>(attnb, Wt, out, 2048, 5120, 4096);
}

// Round 2
// 572.920 us; speedup vs baseline: 1.3285x; 1.3285x over previous
//
#include <hip/hip_runtime.h>

typedef unsigned short u16;
typedef unsigned int   u32;
typedef __bf16 bf16x8 __attribute__((ext_vector_type(8)));
typedef float  f32x4  __attribute__((ext_vector_type(4)));
typedef u16    u16x4  __attribute__((ext_vector_type(4)));
typedef u16    u16x8  __attribute__((ext_vector_type(8)));

// ---------- helpers ----------
__device__ __forceinline__ u16 f2bf(float f) {
  u32 u = __float_as_uint(f);
  u32 r = u + 0x7fffu + ((u >> 16) & 1u);   // RTNE
  return (u16)(r >> 16);
}

__device__ __forceinline__ void gl16(const void* g, void* l) {
  __builtin_amdgcn_global_load_lds((__attribute__((address_space(1))) void*)(g),
                                   (__attribute__((address_space(3))) void*)(l),
                                   16, 0, 0);
}

#define WAITVM4  asm volatile("s_waitcnt vmcnt(4)" ::: "memory")
#define WAITVM0  asm volatile("s_waitcnt vmcnt(0)" ::: "memory")
#define WAITLG0  asm volatile("s_waitcnt lgkmcnt(0)" ::: "memory")
#define BAR()    asm volatile("s_barrier" ::: "memory")
#define SCHEDB() __builtin_amdgcn_sched_barrier(0)

// ---------- fp32 -> bf16 elementwise (layout preserving) ----------
__global__ __launch_bounds__(256) void cvt_f32_bf16(const float* __restrict__ x,
                                                    u16* __restrict__ y, int n4) {
  for (int i = blockIdx.x * 256 + threadIdx.x; i < n4; i += gridDim.x * 256) {
    float4 v = ((const float4*)x)[i];
    u16x4 o;
    o[0] = f2bf(v.x); o[1] = f2bf(v.y); o[2] = f2bf(v.z); o[3] = f2bf(v.w);
    ((u16x4*)y)[i] = o;
  }
}

// ---------- transpose+convert: W[K][N] fp32 -> Wt[Npad][K] bf16 ----------
__global__ __launch_bounds__(256) void transpose_w(const float* __restrict__ W,
                                                   u16* __restrict__ Wt,
                                                   int K, int N, int Npad) {
  __shared__ float tile[32][33];
  const int n0 = blockIdx.x * 32, k0 = blockIdx.y * 32;
  const int tid = threadIdx.x;
  const int r  = tid >> 3;
  const int c4 = (tid & 7) << 2;
  float4 v = make_float4(0.f, 0.f, 0.f, 0.f);
  if (n0 + c4 < N) v = *(const float4*)(W + (size_t)(k0 + r) * N + n0 + c4);
  tile[r][c4 + 0] = v.x; tile[r][c4 + 1] = v.y;
  tile[r][c4 + 2] = v.z; tile[r][c4 + 3] = v.w;
  __syncthreads();
  u16x4 o;
  o[0] = f2bf(tile[c4 + 0][r]); o[1] = f2bf(tile[c4 + 1][r]);
  o[2] = f2bf(tile[c4 + 2][r]); o[3] = f2bf(tile[c4 + 3][r]);
  *(u16x4*)(Wt + (size_t)(n0 + r) * K + k0 + c4) = o;
}

// ---------- GEMM 128x128 (2-phase, for small-N) ----------
__global__ __launch_bounds__(256) void gemm_bt(const u16* __restrict__ A,
                                               const u16* __restrict__ Bt,
                                               float* __restrict__ C,
                                               int M, int N, int K) {
  __shared__ u16 As[128 * 64];
  __shared__ u16 Bs[128 * 64];
  const int tid = threadIdx.x;
  const int lane = tid & 63, w = tid >> 6;
  const int n0 = blockIdx.x << 7, m0 = blockIdx.y << 7;
  const int wr = w >> 1, wc = w & 1;
  const int lr = lane & 15, lg = lane >> 4;
  f32x4 acc[4][4] = {};
  const int nkt = K >> 6;
  const char* Ab = (const char*)A;
  const char* Bb = (const char*)Bt;
  const int stageOff = (w << 10) + (lane << 4);
  for (int kt = 0; kt < nkt; ++kt) {
    __syncthreads();
    const size_t kb = (size_t)kt << 7;
    #pragma unroll
    for (int o = 0; o < 16384; o += 4096) {
      int ofs = stageOff + o;
      int row = ofs >> 7;
      int cb  = ofs & 127;
      gl16(Ab + (size_t)(m0 + row) * K * 2 + kb + cb, (char*)As + ofs);
      gl16(Bb + (size_t)(n0 + row) * K * 2 + kb + cb, (char*)Bs + ofs);
    }
    __syncthreads();
    bf16x8 a[4][2], b[4][2];
    #pragma unroll
    for (int m = 0; m < 4; ++m)
      #pragma unroll
      for (int kf = 0; kf < 2; ++kf)
        a[m][kf] = *(const bf16x8*)(As + ((wr * 64 + m * 16 + lr) * 64 + kf * 32 + lg * 8));
    #pragma unroll
    for (int n = 0; n < 4; ++n)
      #pragma unroll
      for (int kf = 0; kf < 2; ++kf)
        b[n][kf] = *(const bf16x8*)(Bs + ((wc * 64 + n * 16 + lr) * 64 + kf * 32 + lg * 8));
    #pragma unroll
    for (int kf = 0; kf < 2; ++kf)
      #pragma unroll
      for (int m = 0; m < 4; ++m)
        #pragma unroll
        for (int n = 0; n < 4; ++n)
          acc[m][n] = __builtin_amdgcn_mfma_f32_16x16x32_bf16(a[m][kf], b[n][kf], acc[m][n], 0, 0, 0);
  }
  #pragma unroll
  for (int m = 0; m < 4; ++m) {
    const int row0 = m0 + wr * 64 + m * 16 + lg * 4;
    #pragma unroll
    for (int n = 0; n < 4; ++n) {
      const int col = n0 + wc * 64 + n * 16 + lr;
      #pragma unroll
      for (int r = 0; r < 4; ++r)
        C[(size_t)(row0 + r) * N + col] = acc[m][n][r];
    }
  }
}

// ---------- GEMM 256x256, BK=64, 8 waves, 8-phase counted-vmcnt (m201 port) ----------
// LDS: A: 4 half-slots of 16KB (parity,half), B: same at +64KB. Swizzle:
// logical (row, s16) -> physical s16 ^ (row&7); applied on ds_read AND on the
// pre-swizzled global source col for the linear global_load_lds dest (rule 21).
__global__ __launch_bounds__(512, 2) void gemm_bt_8ph(const u16* __restrict__ A,
                                                      const u16* __restrict__ Bt,
                                                      float* __restrict__ C,
                                                      int M, int N, int K) {
  __shared__ char lds[131072];
  const int nkt = K >> 6;
  const int tid = threadIdx.x;
  const int lane = tid & 63, wid = tid >> 6;
  const int wr = wid >> 2, wc = wid & 3;
  const int lr = lane & 15, lg = lane >> 4;

  const int nbx = N >> 8, nby = M >> 8;
  const int nwg = nbx * nby;
  const int wg  = blockIdx.x;
  const int swz = ((nwg & 7) == 0) ? ((wg & 7) * (nwg >> 3) + (wg >> 3)) : wg;
  const int bx = swz % nbx, by = swz / nbx;
  const int m0 = by << 8, n0 = bx << 8;

  const size_t rs = (size_t)K << 1;          // byte row stride (A and Bt)
  const char* Ab = (const char*)A;
  const char* Bb = (const char*)Bt;

  // staging constants: dest ofs (linear), pre-swizzled source col
  const int sofs = tid << 4;                 // 0..8191 (round 0)
  const int srow = sofs >> 7;                // 0..63
  const int scol = ((((sofs >> 4) & 7) ^ (srow & 7)) << 4);

  // fragment-read constants (swizzled col-slot per kf)
  const int axor = lr & 7;
  const int sx0 = (lg ^ axor) << 4;
  const int sx1 = ((4 | lg) ^ axor) << 4;
  const int bcolbase = (wc & 1) << 13;       // 64-row offset within B half-slot

  f32x4 acc[8][4] = {};

#define ASL(p,h) ((((p) << 1) | (h)) << 14)
#define BSL(p,h) (65536 + ((((p) << 1) | (h)) << 14))
#define STAGE_HALF(gb, grow0, kt, slot)                                              \
  { const char* _s = (gb) + (size_t)(grow0) * rs + ((size_t)(kt) << 7) + scol;       \
    gl16(_s, lds + (slot) + sofs);                                                   \
    gl16(_s + (rs << 6), lds + (slot) + sofs + 8192); }

  // prologue: A(0)h0,h1  B(0)h0,h1  B(1)h0,h1
  STAGE_HALF(Ab, m0 + srow,       0, ASL(0,0));
  STAGE_HALF(Ab, m0 + 128 + srow, 0, ASL(0,1));
  STAGE_HALF(Bb, n0 + srow,       0, BSL(0,0));
  STAGE_HALF(Bb, n0 + 128 + srow, 0, BSL(0,1));
  if (nkt > 1) {
    STAGE_HALF(Bb, n0 + srow,       1, BSL(1,0));
    STAGE_HALF(Bb, n0 + 128 + srow, 1, BSL(1,1));
    WAITVM4;
  } else {
    WAITVM0;
  }
  BAR();

  for (int b = 0; b < nkt; ++b) {
    const int p = b & 1;
    const int abase = ASL(p, wr);
    const int bbase = BSL(p, (wc >> 1)) + bcolbase;
    bf16x8 aR[4][2], bR[4][2];

    // ---- phase 1 (mh0,nh0): read A m0-3 + B n0-1; stage A(b+1) h0
    #pragma unroll
    for (int m = 0; m < 4; ++m) {
      aR[m][0] = *(const bf16x8*)(lds + abase + (m * 16 + lr) * 128 + sx0);
      aR[m][1] = *(const bf16x8*)(lds + abase + (m * 16 + lr) * 128 + sx1);
    }
    #pragma unroll
    for (int n = 0; n < 2; ++n) {
      bR[n][0] = *(const bf16x8*)(lds + bbase + (n * 16 + lr) * 128 + sx0);
      bR[n][1] = *(const bf16x8*)(lds + bbase + (n * 16 + lr) * 128 + sx1);
    }
    if (b + 1 < nkt) { STAGE_HALF(Ab, m0 + srow, b + 1, ASL((b + 1) & 1, 0)); }
    BAR(); WAITLG0; SCHEDB();
    __builtin_amdgcn_s_setprio(1);
    #pragma unroll
    for (int kf = 0; kf < 2; ++kf)
      #pragma unroll
      for (int m = 0; m < 4; ++m)
        #pragma unroll
        for (int n = 0; n < 2; ++n)
          acc[m][n] = __builtin_amdgcn_mfma_f32_16x16x32_bf16(aR[m][kf], bR[n][kf], acc[m][n], 0, 0, 0);
    __builtin_amdgcn_s_setprio(0); SCHEDB();
    BAR();

    // ---- phase 2 (mh0,nh1): read B n2-3; stage A(b+1) h1
    #pragma unroll
    for (int n = 2; n < 4; ++n) {
      bR[n][0] = *(const bf16x8*)(lds + bbase + (n * 16 + lr) * 128 + sx0);
      bR[n][1] = *(const bf16x8*)(lds + bbase + (n * 16 + lr) * 128 + sx1);
    }
    if (b + 1 < nkt) { STAGE_HALF(Ab, m0 + 128 + srow, b + 1, ASL((b + 1) & 1, 1)); }
    BAR(); WAITLG0; SCHEDB();
    __builtin_amdgcn_s_setprio(1);
    #pragma unroll
    for (int kf = 0; kf < 2; ++kf)
      #pragma unroll
      for (int m = 0; m < 4; ++m)
        #pragma unroll
        for (int n = 2; n < 4; ++n)
          acc[m][n] = __builtin_amdgcn_mfma_f32_16x16x32_bf16(aR[m][kf], bR[n][kf], acc[m][n], 0, 0, 0);
    __builtin_amdgcn_s_setprio(0); SCHEDB();
    BAR();

    // ---- phase 3 (mh1,nh0): read A m4-7 (reuse B n0-1); stage B(b+2) h0
    #pragma unroll
    for (int m = 0; m < 4; ++m) {
      aR[m][0] = *(const bf16x8*)(lds + abase + ((m + 4) * 16 + lr) * 128 + sx0);
      aR[m][1] = *(const bf16x8*)(lds + abase + ((m + 4) * 16 + lr) * 128 + sx1);
    }
    if (b + 2 < nkt) { STAGE_HALF(Bb, n0 + srow, b + 2, BSL(p, 0)); }
    BAR(); WAITLG0; SCHEDB();
    __builtin_amdgcn_s_setprio(1);
    #pragma unroll
    for (int kf = 0; kf < 2; ++kf)
      #pragma unroll
      for (int m = 0; m < 4; ++m)
        #pragma unroll
        for (int n = 0; n < 2; ++n)
          acc[m + 4][n] = __builtin_amdgcn_mfma_f32_16x16x32_bf16(aR[m][kf], bR[n][kf], acc[m + 4][n], 0, 0, 0);
    __builtin_amdgcn_s_setprio(0); SCHEDB();
    BAR();

    // ---- phase 4 (mh1,nh1): no reads; stage B(b+2) h1; block-end counted vmcnt
    if (b + 2 < nkt) { STAGE_HALF(Bb, n0 + 128 + srow, b + 2, BSL(p, 1)); }
    BAR(); SCHEDB();
    __builtin_amdgcn_s_setprio(1);
    #pragma unroll
    for (int kf = 0; kf < 2; ++kf)
      #pragma unroll
      for (int m = 0; m < 4; ++m)
        #pragma unroll
        for (int n = 2; n < 4; ++n)
          acc[m + 4][n] = __builtin_amdgcn_mfma_f32_16x16x32_bf16(aR[m][kf], bR[n][kf], acc[m + 4][n], 0, 0, 0);
    __builtin_amdgcn_s_setprio(0); SCHEDB();
    if (b + 2 < nkt) { WAITVM4; } else { WAITVM0; }
    BAR();
  }

  #pragma unroll
  for (int m = 0; m < 8; ++m) {
    const int row0 = m0 + wr * 128 + m * 16 + lg * 4;
    #pragma unroll
    for (int n = 0; n < 4; ++n) {
      const int col = n0 + wc * 64 + n * 16 + lr;
      #pragma unroll
      for (int r = 0; r < 4; ++r)
        C[(size_t)(row0 + r) * N + col] = acc[m][n][r];
    }
  }
#undef ASL
#undef BSL
#undef STAGE_HALF
}

// ---------- RMSNorm for q_c: x rows at stride 2176 (cols 0..1535) -> y bf16 ----------
__global__ __launch_bounds__(256) void norm_q_kernel(const float* __restrict__ x,
                                                     const float* __restrict__ w,
                                                     u16* __restrict__ y) {
  const int row = blockIdx.x, tid = threadIdx.x;
  const float* xr = x + (size_t)row * 2176;
  float v[6]; float ss = 0.f;
  #pragma unroll
  for (int i = 0; i < 6; ++i) { v[i] = xr[tid + i * 256]; ss += v[i] * v[i]; }
  __shared__ float sm[4];
  #pragma unroll
  for (int o = 32; o > 0; o >>= 1) ss += __shfl_down(ss, o, 64);
  if ((tid & 63) == 0) sm[tid >> 6] = ss;
  __syncthreads();
  float tot = sm[0] + sm[1] + sm[2] + sm[3];
  float rs = rsqrtf(tot * (1.f / 1536.f) + 1e-6f);
  #pragma unroll
  for (int i = 0; i < 6; ++i)
    y[(size_t)row * 1536 + tid + i * 256] = f2bf(v[i] * rs * w[tid + i * 256]);
}

// ---------- RMSNorm for compressed kv + RoPE(k_rope): rows at stride 2176 off 1536 ----------
__global__ __launch_bounds__(256) void norm_kv_kernel(const float* __restrict__ kva,
                                                      const float* __restrict__ w,
                                                      const int* __restrict__ pos,
                                                      u16* __restrict__ comp,
                                                      u16* __restrict__ krope) {
  const int row = blockIdx.x, tid = threadIdx.x;
  const float* xr = kva + (size_t)row * 2176 + 1536;
  float v0 = xr[tid], v1 = xr[tid + 256];
  float ss = v0 * v0 + v1 * v1;
  __shared__ float sm[4];
  #pragma unroll
  for (int o = 32; o > 0; o >>= 1) ss += __shfl_down(ss, o, 64);
  if ((tid & 63) == 0) sm[tid >> 6] = ss;
  __syncthreads();
  float tot = sm[0] + sm[1] + sm[2] + sm[3];
  float rs = rsqrtf(tot * (1.f / 512.f) + 1e-6f);
  comp[(size_t)row * 512 + tid]       = f2bf(v0 * rs * w[tid]);
  comp[(size_t)row * 512 + tid + 256] = f2bf(v1 * rs * w[tid + 256]);
  if (tid < 32) {
    float p = (float)pos[row];
    float inv = powf(10000.0f, -(float)(2 * tid) * (1.0f / 64.0f));
    float ang = p * inv;
    float c = cosf(ang), s = sinf(ang);
    float x1 = xr[512 + 2 * tid], x2 = xr[512 + 2 * tid + 1];
    krope[(size_t)row * 64 + 2 * tid]     = f2bf(x1 * c - x2 * s);
    krope[(size_t)row * 64 + 2 * tid + 1] = f2bf(x1 * s + x2 * c);
  }
}

// ---------- RoPE(q) + relayout to q_all[h][t][192] bf16 ----------
__global__ __launch_bounds__(256) void rope_q_kernel(const float* __restrict__ qb,
                                                     const int* __restrict__ pos,
                                                     u16* __restrict__ q_all) {
  const int t = blockIdx.x, tid = threadIdx.x;
  const float* qr = qb + (size_t)t * 6144;
  const float p = (float)pos[t];
  for (int idx = tid; idx < 4096; idx += 256) {
    int h = idx >> 7, d = idx & 127;
    q_all[((size_t)h * 2048 + t) * 192 + d] = f2bf(qr[h * 192 + d]);
  }
  for (int idx = tid; idx < 1024; idx += 256) {
    int h = idx >> 5, i = idx & 31;
    float inv = powf(10000.0f, -(float)(2 * i) * (1.0f / 64.0f));
    float ang = p * inv;
    float c = cosf(ang), s = sinf(ang);
    float x1 = qr[h * 192 + 128 + 2 * i], x2 = qr[h * 192 + 128 + 2 * i + 1];
    size_t ob = ((size_t)h * 2048 + t) * 192 + 128;
    q_all[ob + 2 * i]     = f2bf(x1 * c - x2 * s);
    q_all[ob + 2 * i + 1] = f2bf(x1 * s + x2 * c);
  }
}

// ---------- split kv -> k_all[h][s][200], v_t[h][d][2048] ----------
__global__ __launch_bounds__(256) void kvsplit_kernel(const float* __restrict__ kv,
                                                      const u16* __restrict__ krope,
                                                      u16* __restrict__ k_all,
                                                      u16* __restrict__ v_t) {
  const int h = blockIdx.x & 31, st = blockIdx.x >> 5, tid = threadIdx.x;
  const int s0 = st * 64;
  for (int idx = tid; idx < 8192; idx += 256) {
    int s = idx >> 7, d = idx & 127;
    k_all[((size_t)h * 2048 + s0 + s) * 200 + d] =
        f2bf(kv[(size_t)(s0 + s) * 8192 + h * 256 + d]);
  }
  for (int idx = tid; idx < 4096; idx += 256) {
    int s = idx >> 6, j = idx & 63;
    k_all[((size_t)h * 2048 + s0 + s) * 200 + 128 + j] = krope[(size_t)(s0 + s) * 64 + j];
  }
  __shared__ u16 vs[64][128];
  for (int idx = tid; idx < 8192; idx += 256) {
    int s = idx >> 7, d = idx & 127;
    vs[s][d] = f2bf(kv[(size_t)(s0 + s) * 8192 + h * 256 + 128 + d]);
  }
  __syncthreads();
  const int d = tid >> 1, sh = (tid & 1) * 32;
  u16 tmp[32];
  #pragma unroll
  for (int i = 0; i < 32; ++i) tmp[i] = vs[sh + i][d];
  #pragma unroll
  for (int b = 0; b < 4; ++b) {
    u16x8 o;
    #pragma unroll
    for (int j = 0; j < 8; ++j) o[j] = tmp[b * 8 + j];
    *(u16x8*)(v_t + ((size_t)h * 128 + d) * 2048 + s0 + sh + b * 8) = o;
  }
}

// ---------- flash attention ----------
#define ATT_SCALE 0.07216878364870323f   // 192^-0.5
__global__ __launch_bounds__(256) void attn_fwd(const u16* __restrict__ q_all,
                                                const u16* __restrict__ k_all,
                                                const u16* __restrict__ v_t,
                                                u16* __restrict__ attnb) {
  __shared__ u16 Kl[64 * 200];
  __shared__ u16 Vl[128 * 72];
  __shared__ u16 Pl[4][16 * 72];
  const int tid = threadIdx.x;
  const int lane = tid & 63, w = tid >> 6;
  const int h = blockIdx.x & 31, qt = blockIdx.x >> 5;
  const int lr = lane & 15, lg = lane >> 4;
  const int qrow = qt * 64 + w * 16 + lr;

  bf16x8 qf[6];
  const u16* qb = q_all + ((size_t)h * 2048 + qrow) * 192 + lg * 8;
  #pragma unroll
  for (int kf = 0; kf < 6; ++kf) qf[kf] = *(const bf16x8*)(qb + kf * 32);

  f32x4 O[8] = {};
  float mrow[4] = {-1e30f, -1e30f, -1e30f, -1e30f};
  float lrow[4] = {0.f, 0.f, 0.f, 0.f};
  const char* kh = (const char*)(k_all + (size_t)h * 2048 * 200);
  const char* vh = (const char*)(v_t + (size_t)h * 128 * 2048);
  const int ntile = qt + 1;
  const int stageOff = (w << 10) + (lane << 4);

  for (int st = 0; st < ntile; ++st) {
    const int s0 = st * 64;
    __syncthreads();
    {
      const char* src = kh + (size_t)s0 * 400;
      for (int o = stageOff; o < 25600; o += 4096)
        gl16(src + o, (char*)Kl + o);
    }
    for (int o = stageOff; o < 18432; o += 4096) {
      int row = o / 144;
      int rem = o - row * 144;
      const char* src = vh + (size_t)row * 4096 + (size_t)s0 * 2 + (rem < 128 ? rem : 0);
      gl16(src, (char*)Vl + o);
    }
    __syncthreads();

    f32x4 S[4];
    #pragma unroll
    for (int sb = 0; sb < 4; ++sb) {
      f32x4 a = {};
      #pragma unroll
      for (int kf = 0; kf < 6; ++kf) {
        bf16x8 bk = *(const bf16x8*)(Kl + (sb * 16 + lr) * 200 + kf * 32 + lg * 8);
        a = __builtin_amdgcn_mfma_f32_16x16x32_bf16(qf[kf], bk, a, 0, 0, 0);
      }
      S[sb] = a;
    }

    const int qg0 = qt * 64 + w * 16 + lg * 4;
    #pragma unroll
    for (int sb = 0; sb < 4; ++sb) {
      int sc = s0 + sb * 16 + lr;
      #pragma unroll
      for (int r = 0; r < 4; ++r) {
        float v = S[sb][r] * ATT_SCALE;
        S[sb][r] = (sc > qg0 + r) ? -1e30f : v;
      }
    }

    float tmax[4];
    #pragma unroll
    for (int r = 0; r < 4; ++r) {
      float t = fmaxf(fmaxf(S[0][r], S[1][r]), fmaxf(S[2][r], S[3][r]));
      #pragma unroll
      for (int o2 = 1; o2 < 16; o2 <<= 1) t = fmaxf(t, __shfl_xor(t, o2, 64));
      tmax[r] = t;
    }
    float alpha[4];
    #pragma unroll
    for (int r = 0; r < 4; ++r) {
      float mn = fmaxf(mrow[r], tmax[r]);
      alpha[r] = __expf(mrow[r] - mn);
      mrow[r] = mn;
    }
    float rsum[4] = {0.f, 0.f, 0.f, 0.f};
    #pragma unroll
    for (int sb = 0; sb < 4; ++sb)
      #pragma unroll
      for (int r = 0; r < 4; ++r) {
        float p = __expf(S[sb][r] - mrow[r]);
        S[sb][r] = p;
        rsum[r] += p;
      }
    #pragma unroll
    for (int r = 0; r < 4; ++r) {
      float t = rsum[r];
      #pragma unroll
      for (int o2 = 1; o2 < 16; o2 <<= 1) t += __shfl_xor(t, o2, 64);
      lrow[r] = lrow[r] * alpha[r] + t;
    }
    #pragma unroll
    for (int nb = 0; nb < 8; ++nb)
      #pragma unroll
      for (int r = 0; r < 4; ++r) O[nb][r] *= alpha[r];

    u16* pw = Pl[w];
    #pragma unroll
    for (int sb = 0; sb < 4; ++sb)
      #pragma unroll
      for (int r = 0; r < 4; ++r)
        pw[(lg * 4 + r) * 72 + sb * 16 + lr] = f2bf(S[sb][r]);

    #pragma unroll
    for (int k2 = 0; k2 < 2; ++k2) {
      bf16x8 ap = *(const bf16x8*)(pw + lr * 72 + k2 * 32 + lg * 8);
      #pragma unroll
      for (int nb = 0; nb < 8; ++nb) {
        bf16x8 bv = *(const bf16x8*)(Vl + (nb * 16 + lr) * 72 + k2 * 32 + lg * 8);
        O[nb] = __builtin_amdgcn_mfma_f32_16x16x32_bf16(ap, bv, O[nb], 0, 0, 0);
      }
    }
  }

  const int trow0 = qt * 64 + w * 16 + lg * 4;
  #pragma unroll
  for (int nb = 0; nb < 8; ++nb) {
    const int col = h * 128 + nb * 16 + lr;
    #pragma unroll
    for (int r = 0; r < 4; ++r)
      attnb[(size_t)(trow0 + r) * 4096 + col] = f2bf(O[nb][r] / lrow[r]);
  }
}

// ---------- host ----------
extern "C" void kernel_launch(void* const* d_in, const int* in_sizes, int n_in,
                              void* d_out, int out_size, void* d_ws, size_t ws_size,
                              hipStream_t stream) {
  const int*   positions = (const int*)d_in[0];
  const float* hidden    = (const float*)d_in[1];
  const float* w_q_a     = (const float*)d_in[2];
  const float* q_a_norm  = (const float*)d_in[3];
  const float* w_q_b     = (const float*)d_in[4];
  const float* w_kv_a    = (const float*)d_in[5];
  const float* kv_a_norm = (const float*)d_in[6];
  const float* w_kv_b    = (const float*)d_in[7];
  const float* w_o       = (const float*)d_in[8];
  float* out = (float*)d_out;
  char*  ws  = (char*)d_ws;

  u16* hs_bf  = (u16*)(ws + 0);                       // 20,971,520
  u16* Wt     = (u16*)(ws + 20971520);                // 41,943,040 region (reused)
  char* Creg  = ws + 62914560;                        // 67,108,864 region (reused)
  float* qkv_lin = (float*)Creg;                      // 2048*2176*4 = 17,825,792
  float* q_big   = (float*)Creg;                      // 50,331,648 (after norms)
  float* kv_big  = (float*)Creg;                      // 67,108,864 (after rope_q)
  u16* q_c_n  = (u16*)(ws + 130023424);
  u16* comp   = (u16*)(ws + 136314880);
  u16* krope  = (u16*)(ws + 138412032);
  u16* q_all  = (u16*)(ws + 138674176);
  u16* k_all  = (u16*)(ws + 163840000);
  u16* v_t    = (u16*)(ws + 190054400);
  u16* attnb  = (u16*)(ws + 206831616);

  u16* wqa_t  = Wt;                                   // [1536][5120]
  u16* wkva_t = Wt + (size_t)1536 * 5120;             // [640][5120] (contiguous -> [2176][5120])

  // 1) conversions
  cvt_f32_bf16<<<2048, 256, 0, stream>>>(hidden, hs_bf, (2048 * 5120) / 4);
  transpose_w<<<dim3(48, 160), 256, 0, stream>>>(w_q_a,  wqa_t,  5120, 1536, 1536);
  transpose_w<<<dim3(20, 160), 256, 0, stream>>>(w_kv_a, wkva_t, 5120, 576,  640);

  // 2) merged LoRA-A GEMM: [2048][2176] = hs * [wqa|wkva]^T
  gemm_bt<<<dim3(17, 16), 256, 0, stream>>>(hs_bf, wqa_t, qkv_lin, 2048, 2176, 5120);

  // 3) norms (+ k rope)
  norm_q_kernel<<<2048, 256, 0, stream>>>(qkv_lin, q_a_norm, q_c_n);
  norm_kv_kernel<<<2048, 256, 0, stream>>>(qkv_lin, kv_a_norm, positions, comp, krope);

  // 4) q up-projection (8-phase) + rope + relayout
  transpose_w<<<dim3(192, 48), 256, 0, stream>>>(w_q_b, Wt, 1536, 6144, 6144);
  gemm_bt_8ph<<<192, 512, 0, stream>>>(q_c_n, Wt, q_big, 2048, 6144, 1536);
  rope_q_kernel<<<2048, 256, 0, stream>>>(q_big, positions, q_all);

  // 5) kv up-projection (8-phase) + split/relayout
  transpose_w<<<dim3(256, 16), 256, 0, stream>>>(w_kv_b, Wt, 512, 8192, 8192);
  gemm_bt_8ph<<<256, 512, 0, stream>>>(comp, Wt, kv_big, 2048, 8192, 512);
  kvsplit_kernel<<<1024, 256, 0, stream>>>(kv_big, krope, k_all, v_t);

  // 6) attention
  transpose_w<<<dim3(160, 128), 256, 0, stream>>>(w_o, Wt, 4096, 5120, 5120);
  attn_fwd<<<1024, 256, 0, stream>>>(q_all, k_all, v_t, attnb);

  // 7) output projection (8-phase, fp32 out)
  gemm_bt_8ph<<<160, 512, 0, stream>>>(attnb, Wt, out, 2048, 5120, 4096);
}

// Round 3
// 533.279 us; speedup vs baseline: 1.4272x; 1.0743x over previous
//
#include <hip/hip_runtime.h>

typedef unsigned short u16;
typedef unsigned int   u32;
typedef __bf16 bf16x8 __attribute__((ext_vector_type(8)));
typedef float  f32x4  __attribute__((ext_vector_type(4)));
typedef u16    u16x4  __attribute__((ext_vector_type(4)));
typedef u16    u16x8  __attribute__((ext_vector_type(8)));

// ---------- helpers ----------
__device__ __forceinline__ u16 f2bf(float f) {
  u32 u = __float_as_uint(f);
  u32 r = u + 0x7fffu + ((u >> 16) & 1u);   // RTNE
  return (u16)(r >> 16);
}

__device__ __forceinline__ void gl16(const void* g, void* l) {
  __builtin_amdgcn_global_load_lds((__attribute__((address_space(1))) void*)(g),
                                   (__attribute__((address_space(3))) void*)(l),
                                   16, 0, 0);
}

#define WAITVM4  asm volatile("s_waitcnt vmcnt(4)" ::: "memory")
#define WAITVM0  asm volatile("s_waitcnt vmcnt(0)" ::: "memory")
#define WAITLG0  asm volatile("s_waitcnt lgkmcnt(0)" ::: "memory")
#define BAR()    asm volatile("s_barrier" ::: "memory")
#define SCHEDB() __builtin_amdgcn_sched_barrier(0)

// ---------- fp32 -> bf16 elementwise ----------
__global__ __launch_bounds__(256) void cvt_f32_bf16(const float* __restrict__ x,
                                                    u16* __restrict__ y, int n4) {
  for (int i = blockIdx.x * 256 + threadIdx.x; i < n4; i += gridDim.x * 256) {
    float4 v = ((const float4*)x)[i];
    u16x4 o;
    o[0] = f2bf(v.x); o[1] = f2bf(v.y); o[2] = f2bf(v.z); o[3] = f2bf(v.w);
    ((u16x4*)y)[i] = o;
  }
}

// ---------- transpose+convert: W[K][N] fp32 -> Wt[Npad][K] bf16 ----------
__global__ __launch_bounds__(256) void transpose_w(const float* __restrict__ W,
                                                   u16* __restrict__ Wt,
                                                   int K, int N, int Npad) {
  __shared__ float tile[32][33];
  const int n0 = blockIdx.x * 32, k0 = blockIdx.y * 32;
  const int tid = threadIdx.x;
  const int r  = tid >> 3;
  const int c4 = (tid & 7) << 2;
  float4 v = make_float4(0.f, 0.f, 0.f, 0.f);
  if (n0 + c4 < N) v = *(const float4*)(W + (size_t)(k0 + r) * N + n0 + c4);
  tile[r][c4 + 0] = v.x; tile[r][c4 + 1] = v.y;
  tile[r][c4 + 2] = v.z; tile[r][c4 + 3] = v.w;
  __syncthreads();
  u16x4 o;
  o[0] = f2bf(tile[c4 + 0][r]); o[1] = f2bf(tile[c4 + 1][r]);
  o[2] = f2bf(tile[c4 + 2][r]); o[3] = f2bf(tile[c4 + 3][r]);
  *(u16x4*)(Wt + (size_t)(n0 + r) * K + k0 + c4) = o;
}

// ---------- GEMM 128x128 (2-phase) ----------
__global__ __launch_bounds__(256) void gemm_bt(const u16* __restrict__ A,
                                               const u16* __restrict__ Bt,
                                               float* __restrict__ C,
                                               int M, int N, int K) {
  __shared__ u16 As[128 * 64];
  __shared__ u16 Bs[128 * 64];
  const int tid = threadIdx.x;
  const int lane = tid & 63, w = tid >> 6;
  const int n0 = blockIdx.x << 7, m0 = blockIdx.y << 7;
  const int wr = w >> 1, wc = w & 1;
  const int lr = lane & 15, lg = lane >> 4;
  f32x4 acc[4][4] = {};
  const int nkt = K >> 6;
  const char* Ab = (const char*)A;
  const char* Bb = (const char*)Bt;
  const int stageOff = (w << 10) + (lane << 4);
  for (int kt = 0; kt < nkt; ++kt) {
    __syncthreads();
    const size_t kb = (size_t)kt << 7;
    #pragma unroll
    for (int o = 0; o < 16384; o += 4096) {
      int ofs = stageOff + o;
      int row = ofs >> 7;
      int cb  = ofs & 127;
      gl16(Ab + (size_t)(m0 + row) * K * 2 + kb + cb, (char*)As + ofs);
      gl16(Bb + (size_t)(n0 + row) * K * 2 + kb + cb, (char*)Bs + ofs);
    }
    __syncthreads();
    bf16x8 a[4][2], b[4][2];
    #pragma unroll
    for (int m = 0; m < 4; ++m)
      #pragma unroll
      for (int kf = 0; kf < 2; ++kf)
        a[m][kf] = *(const bf16x8*)(As + ((wr * 64 + m * 16 + lr) * 64 + kf * 32 + lg * 8));
    #pragma unroll
    for (int n = 0; n < 4; ++n)
      #pragma unroll
      for (int kf = 0; kf < 2; ++kf)
        b[n][kf] = *(const bf16x8*)(Bs + ((wc * 64 + n * 16 + lr) * 64 + kf * 32 + lg * 8));
    #pragma unroll
    for (int kf = 0; kf < 2; ++kf)
      #pragma unroll
      for (int m = 0; m < 4; ++m)
        #pragma unroll
        for (int n = 0; n < 4; ++n)
          acc[m][n] = __builtin_amdgcn_mfma_f32_16x16x32_bf16(a[m][kf], b[n][kf], acc[m][n], 0, 0, 0);
  }
  #pragma unroll
  for (int m = 0; m < 4; ++m) {
    const int row0 = m0 + wr * 64 + m * 16 + lg * 4;
    #pragma unroll
    for (int n = 0; n < 4; ++n) {
      const int col = n0 + wc * 64 + n * 16 + lr;
      #pragma unroll
      for (int r = 0; r < 4; ++r)
        C[(size_t)(row0 + r) * N + col] = acc[m][n][r];
    }
  }
}

// ---------- GEMM 256x256, BK=64, 8 waves, 8-phase counted-vmcnt ----------
__global__ __launch_bounds__(512, 2) void gemm_bt_8ph(const u16* __restrict__ A,
                                                      const u16* __restrict__ Bt,
                                                      float* __restrict__ C,
                                                      int M, int N, int K) {
  __shared__ char lds[131072];
  const int nkt = K >> 6;
  const int tid = threadIdx.x;
  const int lane = tid & 63, wid = tid >> 6;
  const int wr = wid >> 2, wc = wid & 3;
  const int lr = lane & 15, lg = lane >> 4;

  const int nbx = N >> 8, nby = M >> 8;
  const int nwg = nbx * nby;
  const int wg  = blockIdx.x;
  const int swz = ((nwg & 7) == 0) ? ((wg & 7) * (nwg >> 3) + (wg >> 3)) : wg;
  const int bx = swz % nbx, by = swz / nbx;
  const int m0 = by << 8, n0 = bx << 8;

  const size_t rs = (size_t)K << 1;
  const char* Ab = (const char*)A;
  const char* Bb = (const char*)Bt;

  const int sofs = tid << 4;
  const int srow = sofs >> 7;
  const int scol = ((((sofs >> 4) & 7) ^ (srow & 7)) << 4);

  const int axor = lr & 7;
  const int sx0 = (lg ^ axor) << 4;
  const int sx1 = ((4 | lg) ^ axor) << 4;
  const int bcolbase = (wc & 1) << 13;

  f32x4 acc[8][4] = {};

#define ASL(p,h) ((((p) << 1) | (h)) << 14)
#define BSL(p,h) (65536 + ((((p) << 1) | (h)) << 14))
#define STAGE_HALF(gb, grow0, kt, slot)                                              \
  { const char* _s = (gb) + (size_t)(grow0) * rs + ((size_t)(kt) << 7) + scol;       \
    gl16(_s, lds + (slot) + sofs);                                                   \
    gl16(_s + (rs << 6), lds + (slot) + sofs + 8192); }

  STAGE_HALF(Ab, m0 + srow,       0, ASL(0,0));
  STAGE_HALF(Ab, m0 + 128 + srow, 0, ASL(0,1));
  STAGE_HALF(Bb, n0 + srow,       0, BSL(0,0));
  STAGE_HALF(Bb, n0 + 128 + srow, 0, BSL(0,1));
  if (nkt > 1) {
    STAGE_HALF(Bb, n0 + srow,       1, BSL(1,0));
    STAGE_HALF(Bb, n0 + 128 + srow, 1, BSL(1,1));
    WAITVM4;
  } else {
    WAITVM0;
  }
  BAR();

  for (int b = 0; b < nkt; ++b) {
    const int p = b & 1;
    const int abase = ASL(p, wr);
    const int bbase = BSL(p, (wc >> 1)) + bcolbase;
    bf16x8 aR[4][2], bR[4][2];

    #pragma unroll
    for (int m = 0; m < 4; ++m) {
      aR[m][0] = *(const bf16x8*)(lds + abase + (m * 16 + lr) * 128 + sx0);
      aR[m][1] = *(const bf16x8*)(lds + abase + (m * 16 + lr) * 128 + sx1);
    }
    #pragma unroll
    for (int n = 0; n < 2; ++n) {
      bR[n][0] = *(const bf16x8*)(lds + bbase + (n * 16 + lr) * 128 + sx0);
      bR[n][1] = *(const bf16x8*)(lds + bbase + (n * 16 + lr) * 128 + sx1);
    }
    if (b + 1 < nkt) { STAGE_HALF(Ab, m0 + srow, b + 1, ASL((b + 1) & 1, 0)); }
    BAR(); WAITLG0; SCHEDB();
    __builtin_amdgcn_s_setprio(1);
    #pragma unroll
    for (int kf = 0; kf < 2; ++kf)
      #pragma unroll
      for (int m = 0; m < 4; ++m)
        #pragma unroll
        for (int n = 0; n < 2; ++n)
          acc[m][n] = __builtin_amdgcn_mfma_f32_16x16x32_bf16(aR[m][kf], bR[n][kf], acc[m][n], 0, 0, 0);
    __builtin_amdgcn_s_setprio(0); SCHEDB();
    BAR();

    #pragma unroll
    for (int n = 2; n < 4; ++n) {
      bR[n][0] = *(const bf16x8*)(lds + bbase + (n * 16 + lr) * 128 + sx0);
      bR[n][1] = *(const bf16x8*)(lds + bbase + (n * 16 + lr) * 128 + sx1);
    }
    if (b + 1 < nkt) { STAGE_HALF(Ab, m0 + 128 + srow, b + 1, ASL((b + 1) & 1, 1)); }
    BAR(); WAITLG0; SCHEDB();
    __builtin_amdgcn_s_setprio(1);
    #pragma unroll
    for (int kf = 0; kf < 2; ++kf)
      #pragma unroll
      for (int m = 0; m < 4; ++m)
        #pragma unroll
        for (int n = 2; n < 4; ++n)
          acc[m][n] = __builtin_amdgcn_mfma_f32_16x16x32_bf16(aR[m][kf], bR[n][kf], acc[m][n], 0, 0, 0);
    __builtin_amdgcn_s_setprio(0); SCHEDB();
    BAR();

    #pragma unroll
    for (int m = 0; m < 4; ++m) {
      aR[m][0] = *(const bf16x8*)(lds + abase + ((m + 4) * 16 + lr) * 128 + sx0);
      aR[m][1] = *(const bf16x8*)(lds + abase + ((m + 4) * 16 + lr) * 128 + sx1);
    }
    if (b + 2 < nkt) { STAGE_HALF(Bb, n0 + srow, b + 2, BSL(p, 0)); }
    BAR(); WAITLG0; SCHEDB();
    __builtin_amdgcn_s_setprio(1);
    #pragma unroll
    for (int kf = 0; kf < 2; ++kf)
      #pragma unroll
      for (int m = 0; m < 4; ++m)
        #pragma unroll
        for (int n = 0; n < 2; ++n)
          acc[m + 4][n] = __builtin_amdgcn_mfma_f32_16x16x32_bf16(aR[m][kf], bR[n][kf], acc[m + 4][n], 0, 0, 0);
    __builtin_amdgcn_s_setprio(0); SCHEDB();
    BAR();

    if (b + 2 < nkt) { STAGE_HALF(Bb, n0 + 128 + srow, b + 2, BSL(p, 1)); }
    BAR(); SCHEDB();
    __builtin_amdgcn_s_setprio(1);
    #pragma unroll
    for (int kf = 0; kf < 2; ++kf)
      #pragma unroll
      for (int m = 0; m < 4; ++m)
        #pragma unroll
        for (int n = 2; n < 4; ++n)
          acc[m + 4][n] = __builtin_amdgcn_mfma_f32_16x16x32_bf16(aR[m][kf], bR[n][kf], acc[m + 4][n], 0, 0, 0);
    __builtin_amdgcn_s_setprio(0); SCHEDB();
    if (b + 2 < nkt) { WAITVM4; } else { WAITVM0; }
    BAR();
  }

  #pragma unroll
  for (int m = 0; m < 8; ++m) {
    const int row0 = m0 + wr * 128 + m * 16 + lg * 4;
    #pragma unroll
    for (int n = 0; n < 4; ++n) {
      const int col = n0 + wc * 64 + n * 16 + lr;
      #pragma unroll
      for (int r = 0; r < 4; ++r)
        C[(size_t)(row0 + r) * N + col] = acc[m][n][r];
    }
  }
#undef ASL
#undef BSL
#undef STAGE_HALF
}

// ---------- RMSNorm q ----------
__global__ __launch_bounds__(256) void norm_q_kernel(const float* __restrict__ x,
                                                     const float* __restrict__ w,
                                                     u16* __restrict__ y) {
  const int row = blockIdx.x, tid = threadIdx.x;
  const float* xr = x + (size_t)row * 2176;
  float v[6]; float ss = 0.f;
  #pragma unroll
  for (int i = 0; i < 6; ++i) { v[i] = xr[tid + i * 256]; ss += v[i] * v[i]; }
  __shared__ float sm[4];
  #pragma unroll
  for (int o = 32; o > 0; o >>= 1) ss += __shfl_down(ss, o, 64);
  if ((tid & 63) == 0) sm[tid >> 6] = ss;
  __syncthreads();
  float tot = sm[0] + sm[1] + sm[2] + sm[3];
  float rs = rsqrtf(tot * (1.f / 1536.f) + 1e-6f);
  #pragma unroll
  for (int i = 0; i < 6; ++i)
    y[(size_t)row * 1536 + tid + i * 256] = f2bf(v[i] * rs * w[tid + i * 256]);
}

// ---------- RMSNorm kv + RoPE(k) ----------
__global__ __launch_bounds__(256) void norm_kv_kernel(const float* __restrict__ kva,
                                                      const float* __restrict__ w,
                                                      const int* __restrict__ pos,
                                                      u16* __restrict__ comp,
                                                      u16* __restrict__ krope) {
  const int row = blockIdx.x, tid = threadIdx.x;
  const float* xr = kva + (size_t)row * 2176 + 1536;
  float v0 = xr[tid], v1 = xr[tid + 256];
  float ss = v0 * v0 + v1 * v1;
  __shared__ float sm[4];
  #pragma unroll
  for (int o = 32; o > 0; o >>= 1) ss += __shfl_down(ss, o, 64);
  if ((tid & 63) == 0) sm[tid >> 6] = ss;
  __syncthreads();
  float tot = sm[0] + sm[1] + sm[2] + sm[3];
  float rs = rsqrtf(tot * (1.f / 512.f) + 1e-6f);
  comp[(size_t)row * 512 + tid]       = f2bf(v0 * rs * w[tid]);
  comp[(size_t)row * 512 + tid + 256] = f2bf(v1 * rs * w[tid + 256]);
  if (tid < 32) {
    float p = (float)pos[row];
    float inv = powf(10000.0f, -(float)(2 * tid) * (1.0f / 64.0f));
    float ang = p * inv;
    float c = cosf(ang), s = sinf(ang);
    float x1 = xr[512 + 2 * tid], x2 = xr[512 + 2 * tid + 1];
    krope[(size_t)row * 64 + 2 * tid]     = f2bf(x1 * c - x2 * s);
    krope[(size_t)row * 64 + 2 * tid + 1] = f2bf(x1 * s + x2 * c);
  }
}

// ---------- RoPE(q) + relayout q_all[h][t][192] ----------
__global__ __launch_bounds__(256) void rope_q_kernel(const float* __restrict__ qb,
                                                     const int* __restrict__ pos,
                                                     u16* __restrict__ q_all) {
  const int t = blockIdx.x, tid = threadIdx.x;
  const float* qr = qb + (size_t)t * 6144;
  const float p = (float)pos[t];
  for (int idx = tid; idx < 4096; idx += 256) {
    int h = idx >> 7, d = idx & 127;
    q_all[((size_t)h * 2048 + t) * 192 + d] = f2bf(qr[h * 192 + d]);
  }
  for (int idx = tid; idx < 1024; idx += 256) {
    int h = idx >> 5, i = idx & 31;
    float inv = powf(10000.0f, -(float)(2 * i) * (1.0f / 64.0f));
    float ang = p * inv;
    float c = cosf(ang), s = sinf(ang);
    float x1 = qr[h * 192 + 128 + 2 * i], x2 = qr[h * 192 + 128 + 2 * i + 1];
    size_t ob = ((size_t)h * 2048 + t) * 192 + 128;
    q_all[ob + 2 * i]     = f2bf(x1 * c - x2 * s);
    q_all[ob + 2 * i + 1] = f2bf(x1 * s + x2 * c);
  }
}

// ---------- split kv -> k_all[h][s][200], v_t[h][d][2048] ----------
__global__ __launch_bounds__(256) void kvsplit_kernel(const float* __restrict__ kv,
                                                      const u16* __restrict__ krope,
                                                      u16* __restrict__ k_all,
                                                      u16* __restrict__ v_t) {
  const int h = blockIdx.x & 31, st = blockIdx.x >> 5, tid = threadIdx.x;
  const int s0 = st * 64;
  for (int idx = tid; idx < 8192; idx += 256) {
    int s = idx >> 7, d = idx & 127;
    k_all[((size_t)h * 2048 + s0 + s) * 200 + d] =
        f2bf(kv[(size_t)(s0 + s) * 8192 + h * 256 + d]);
  }
  for (int idx = tid; idx < 4096; idx += 256) {
    int s = idx >> 6, j = idx & 63;
    k_all[((size_t)h * 2048 + s0 + s) * 200 + 128 + j] = krope[(size_t)(s0 + s) * 64 + j];
  }
  __shared__ u16 vs[64][128];
  for (int idx = tid; idx < 8192; idx += 256) {
    int s = idx >> 7, d = idx & 127;
    vs[s][d] = f2bf(kv[(size_t)(s0 + s) * 8192 + h * 256 + 128 + d]);
  }
  __syncthreads();
  const int d = tid >> 1, sh = (tid & 1) * 32;
  u16 tmp[32];
  #pragma unroll
  for (int i = 0; i < 32; ++i) tmp[i] = vs[sh + i][d];
  #pragma unroll
  for (int b = 0; b < 4; ++b) {
    u16x8 o;
    #pragma unroll
    for (int j = 0; j < 8; ++j) o[j] = tmp[b * 8 + j];
    *(u16x8*)(v_t + ((size_t)h * 128 + d) * 2048 + s0 + sh + b * 8) = o;
  }
}

// ---------- flash attention: 8 waves, 128q x 64s tiles, dbuf, swapped-QK ----------
// scale * log2(e) = 192^-0.5 * 1.44269504
#define SCL2 0.10412706f
#define THR2 11.5f
__global__ __launch_bounds__(512, 2) void attn_fwd(const u16* __restrict__ q_all,
                                                   const u16* __restrict__ k_all,
                                                   const u16* __restrict__ v_t,
                                                   u16* __restrict__ attnb) {
  // LDS: buf0 [K 25600 | V 18432] buf1 [same] | P 8*2304  = 106496
  __shared__ __align__(16) char lds[106496];
  const int tid = threadIdx.x;
  const int lane = tid & 63, wid = tid >> 6;
  const int lr = lane & 15, lg = lane >> 4;
  const int h = blockIdx.x & 31, bq = blockIdx.x >> 5;

  const char* kh = (const char*)(k_all + (size_t)h * 2048 * 200);
  const char* vh = (const char*)(v_t + (size_t)h * 128 * 2048);
  char* Pw = lds + 88064 + wid * 2304;

  // staging slot precompute: 2752 16B chunks (K 0..1599 | V 1600..2751), 43 wave-calls
  const int nCalls = (wid < 3) ? 6 : 5;
  const char* gp[6]; int cofs[6]; int isK[6];
  #pragma unroll
  for (int ii = 0; ii < 6; ++ii) {
    int i = wid + (ii << 3);
    if (i < 43) {
      int c = (i << 6) + lane;
      cofs[ii] = c << 4;
      if (c < 1600) { gp[ii] = kh + ((size_t)c << 4); isK[ii] = 1; }
      else {
        int cv = c - 1600;
        int row = cv / 9, sub = cv - row * 9;
        gp[ii] = vh + ((size_t)row << 12) + ((sub < 8) ? (sub << 4) : 0);
        isK[ii] = 0;
      }
    } else { gp[ii] = kh; cofs[ii] = 0; isK[ii] = 1; }
  }

#define STAGE(s0_, bOff_)                                                       \
  { int _sk = (s0_) * 400, _sv = (s0_) * 2;                                     \
    _Pragma("unroll")                                                           \
    for (int ii = 0; ii < 6; ++ii)                                              \
      if (ii < nCalls)                                                          \
        gl16(gp[ii] + (isK[ii] ? _sk : _sv), lds + (bOff_) + cofs[ii]); }

#define WAITSTAGE                                                               \
  { if (wid < 3) { asm volatile("s_waitcnt vmcnt(6)" ::: "memory"); }           \
    else        { asm volatile("s_waitcnt vmcnt(5)" ::: "memory"); } }

  const int kRd = lr * 400 + lg * 16;           // K fragment base (A operand)
  const int vRd = lr * 144 + lg * 16;           // V fragment base (B operand)
  const int pRd = lr * 144 + lg * 16;           // P fragment base (A operand)
  const int pWr = lr * 144 + lg * 8;            // P write base

  #pragma unroll
  for (int half = 0; half < 2; ++half) {
    const int qt = half ? (15 - bq) : bq;
    const int qb0 = qt << 7;
    const int nt = 2 * qt + 2;
    const int qlane = qb0 + wid * 16 + lr;      // this lane's q row (S domain)
    const int qwmin = qb0 + wid * 16;

    // load Q fragments (B operand: lane holds Q[q=lr][k=lg*8..])
    bf16x8 qf[6];
    const u16* qptr = q_all + ((size_t)h * 2048 + qlane) * 192 + lg * 8;
    #pragma unroll
    for (int kf = 0; kf < 6; ++kf) qf[kf] = *(const bf16x8*)(qptr + kf * 32);

    f32x4 O[8] = {};
    float m = -1e30f, l = 0.f;

    STAGE(0, 0);
    for (int st = 0; st < nt; ++st) {
      const int s0 = st << 6;
      const int bOff = (st & 1) * 44032;
      if (st + 1 < nt) {
        STAGE((st + 1) << 6, ((st + 1) & 1) * 44032);
        WAITSTAGE;
      } else {
        WAITVM0;
      }
      BAR();

      const bool active = (s0 <= qwmin + 15);
      if (active) {
        const char* Kb = lds + bOff;
        const char* Vb = lds + bOff + 25600;

        // S = K * Q^T  (swapped: lane holds S[k=s0+sb*16+lg*4+r][q=lr])
        f32x4 S[4];
        #pragma unroll
        for (int sb = 0; sb < 4; ++sb) {
          f32x4 a = {};
          #pragma unroll
          for (int kf = 0; kf < 6; ++kf) {
            bf16x8 kfr = *(const bf16x8*)(Kb + kRd + sb * 6400 + kf * 64);
            a = __builtin_amdgcn_mfma_f32_16x16x32_bf16(kfr, qf[kf], a, 0, 0, 0);
          }
          S[sb] = a;
        }

        // scale (log2 domain) + causal mask (diagonal-touching waves only)
        if (s0 + 63 > qwmin) {
          const int kb0 = s0 + lg * 4;
          #pragma unroll
          for (int sb = 0; sb < 4; ++sb)
            #pragma unroll
            for (int r = 0; r < 4; ++r) {
              int k = kb0 + sb * 16 + r;
              S[sb][r] = (k > qlane) ? -1e30f : S[sb][r] * SCL2;
            }
        } else {
          #pragma unroll
          for (int sb = 0; sb < 4; ++sb)
            #pragma unroll
            for (int r = 0; r < 4; ++r) S[sb][r] *= SCL2;
        }

        // row max: in-lane 16 + cross-lg
        float mx = S[0][0];
        #pragma unroll
        for (int sb = 0; sb < 4; ++sb)
          #pragma unroll
          for (int r = 0; r < 4; ++r) mx = fmaxf(mx, S[sb][r]);
        mx = fmaxf(mx, __shfl_xor(mx, 16, 64));
        mx = fmaxf(mx, __shfl_xor(mx, 32, 64));

        const bool skip = __all(mx <= m + THR2);
        float alpha = 1.f;
        if (!skip) { float mn = fmaxf(m, mx); alpha = exp2f(m - mn); m = mn; }

        float ps = 0.f;
        #pragma unroll
        for (int sb = 0; sb < 4; ++sb)
          #pragma unroll
          for (int r = 0; r < 4; ++r) {
            float pv = exp2f(S[sb][r] - m);
            S[sb][r] = pv;
            ps += pv;
          }
        ps += __shfl_xor(ps, 16, 64);
        ps += __shfl_xor(ps, 32, 64);
        l = l * alpha + ps;

        if (!skip) {
          float aO[4];
          #pragma unroll
          for (int r = 0; r < 4; ++r) aO[r] = __shfl(alpha, lg * 4 + r, 64);
          #pragma unroll
          for (int nb = 0; nb < 8; ++nb)
            #pragma unroll
            for (int r = 0; r < 4; ++r) O[nb][r] *= aO[r];
        }

        // pack P -> LDS (row q=lr, cols sb*16+lg*4 .. +3)
        #pragma unroll
        for (int sb = 0; sb < 4; ++sb) {
          u32 p01, p23;
          asm("v_cvt_pk_bf16_f32 %0, %1, %2" : "=v"(p01) : "v"(S[sb][0]), "v"(S[sb][1]));
          asm("v_cvt_pk_bf16_f32 %0, %1, %2" : "=v"(p23) : "v"(S[sb][2]), "v"(S[sb][3]));
          *(uint2*)(Pw + pWr + sb * 32) = make_uint2(p01, p23);
        }

        // O += P * V
        #pragma unroll
        for (int k2 = 0; k2 < 2; ++k2) {
          bf16x8 pa = *(const bf16x8*)(Pw + pRd + k2 * 64);
          #pragma unroll
          for (int nb = 0; nb < 8; ++nb) {
            bf16x8 vf = *(const bf16x8*)(Vb + vRd + nb * 2304 + k2 * 64);
            O[nb] = __builtin_amdgcn_mfma_f32_16x16x32_bf16(pa, vf, O[nb], 0, 0, 0);
          }
        }
      }
      BAR();
    }

    // epilogue: O rows are q = qb0 + wid*16 + lg*4 + r
    float rv[4];
    #pragma unroll
    for (int r = 0; r < 4; ++r) rv[r] = 1.f / __shfl(l, lg * 4 + r, 64);
    #pragma unroll
    for (int nb = 0; nb < 8; ++nb) {
      const int col = h * 128 + nb * 16 + lr;
      #pragma unroll
      for (int r = 0; r < 4; ++r)
        attnb[(size_t)(qb0 + wid * 16 + lg * 4 + r) * 4096 + col] = f2bf(O[nb][r] * rv[r]);
    }
  }
#undef STAGE
#undef WAITSTAGE
}

// ---------- host ----------
extern "C" void kernel_launch(void* const* d_in, const int* in_sizes, int n_in,
                              void* d_out, int out_size, void* d_ws, size_t ws_size,
                              hipStream_t stream) {
  const int*   positions = (const int*)d_in[0];
  const float* hidden    = (const float*)d_in[1];
  const float* w_q_a     = (const float*)d_in[2];
  const float* q_a_norm  = (const float*)d_in[3];
  const float* w_q_b     = (const float*)d_in[4];
  const float* w_kv_a    = (const float*)d_in[5];
  const float* kv_a_norm = (const float*)d_in[6];
  const float* w_kv_b    = (const float*)d_in[7];
  const float* w_o       = (const float*)d_in[8];
  float* out = (float*)d_out;
  char*  ws  = (char*)d_ws;

  u16* hs_bf  = (u16*)(ws + 0);
  u16* Wt     = (u16*)(ws + 20971520);
  char* Creg  = ws + 62914560;
  float* qkv_lin = (float*)Creg;
  float* q_big   = (float*)Creg;
  float* kv_big  = (float*)Creg;
  u16* q_c_n  = (u16*)(ws + 130023424);
  u16* comp   = (u16*)(ws + 136314880);
  u16* krope  = (u16*)(ws + 138412032);
  u16* q_all  = (u16*)(ws + 138674176);
  u16* k_all  = (u16*)(ws + 163840000);
  u16* v_t    = (u16*)(ws + 190054400);
  u16* attnb  = (u16*)(ws + 206831616);

  u16* wqa_t  = Wt;
  u16* wkva_t = Wt + (size_t)1536 * 5120;

  cvt_f32_bf16<<<2048, 256, 0, stream>>>(hidden, hs_bf, (2048 * 5120) / 4);
  transpose_w<<<dim3(48, 160), 256, 0, stream>>>(w_q_a,  wqa_t,  5120, 1536, 1536);
  transpose_w<<<dim3(20, 160), 256, 0, stream>>>(w_kv_a, wkva_t, 5120, 576,  640);

  gemm_bt<<<dim3(17, 16), 256, 0, stream>>>(hs_bf, wqa_t, qkv_lin, 2048, 2176, 5120);

  norm_q_kernel<<<2048, 256, 0, stream>>>(qkv_lin, q_a_norm, q_c_n);
  norm_kv_kernel<<<2048, 256, 0, stream>>>(qkv_lin, kv_a_norm, positions, comp, krope);

  transpose_w<<<dim3(192, 48), 256, 0, stream>>>(w_q_b, Wt, 1536, 6144, 6144);
  gemm_bt_8ph<<<192, 512, 0, stream>>>(q_c_n, Wt, q_big, 2048, 6144, 1536);
  rope_q_kernel<<<2048, 256, 0, stream>>>(q_big, positions, q_all);

  transpose_w<<<dim3(256, 16), 256, 0, stream>>>(w_kv_b, Wt, 512, 8192, 8192);
  gemm_bt_8ph<<<256, 512, 0, stream>>>(comp, Wt, kv_big, 2048, 8192, 512);
  kvsplit_kernel<<<1024, 256, 0, stream>>>(kv_big, krope, k_all, v_t);

  transpose_w<<<dim3(160, 128), 256, 0, stream>>>(w_o, Wt, 4096, 5120, 5120);
  attn_fwd<<<256, 512, 0, stream>>>(q_all, k_all, v_t, attnb);

  gemm_bt_8ph<<<160, 512, 0, stream>>>(attnb, Wt, out, 2048, 5120, 4096);
}

// Round 4
// 532.947 us; speedup vs baseline: 1.4281x; 1.0006x over previous
//
#include <hip/hip_runtime.h>

typedef unsigned short u16;
typedef unsigned int   u32;
typedef __bf16 bf16x8 __attribute__((ext_vector_type(8)));
typedef float  f32x4  __attribute__((ext_vector_type(4)));
typedef u16    u16x4  __attribute__((ext_vector_type(4)));
typedef u16    u16x8  __attribute__((ext_vector_type(8)));

// ---------- helpers ----------
__device__ __forceinline__ u16 f2bf(float f) {
  u32 u = __float_as_uint(f);
  u32 r = u + 0x7fffu + ((u >> 16) & 1u);   // RTNE
  return (u16)(r >> 16);
}

__device__ __forceinline__ void gl16(const void* g, void* l) {
  __builtin_amdgcn_global_load_lds((__attribute__((address_space(1))) void*)(g),
                                   (__attribute__((address_space(3))) void*)(l),
                                   16, 0, 0);
}

#define WAITVM4  asm volatile("s_waitcnt vmcnt(4)" ::: "memory")
#define WAITVM0  asm volatile("s_waitcnt vmcnt(0)" ::: "memory")
#define WAITLG0  asm volatile("s_waitcnt lgkmcnt(0)" ::: "memory")
#define BAR()    asm volatile("s_barrier" ::: "memory")
#define SCHEDB() __builtin_amdgcn_sched_barrier(0)

// ---------- fp32 -> bf16 elementwise ----------
__global__ __launch_bounds__(256) void cvt_f32_bf16(const float* __restrict__ x,
                                                    u16* __restrict__ y, int n4) {
  for (int i = blockIdx.x * 256 + threadIdx.x; i < n4; i += gridDim.x * 256) {
    float4 v = ((const float4*)x)[i];
    u16x4 o;
    o[0] = f2bf(v.x); o[1] = f2bf(v.y); o[2] = f2bf(v.z); o[3] = f2bf(v.w);
    ((u16x4*)y)[i] = o;
  }
}

// ---------- transpose+convert: W[K][N] fp32 -> Wt[Npad][K] bf16, 64x64 tiles ----------
// stage: float4 coalesced reads -> LDS [64][68]; out: each thread gathers a
// 16-elem k-run of one n-row, writes 2x16B; lanes 0..3 cover 128B contiguous.
__global__ __launch_bounds__(256) void transpose_w(const float* __restrict__ W,
                                                   u16* __restrict__ Wt,
                                                   int K, int N, int Npad) {
  __shared__ float tile[64][68];
  const int n0 = blockIdx.x * 64, k0 = blockIdx.y * 64;
  const int tid = threadIdx.x;
  {
    const int r = tid >> 2, cb = (tid & 3) << 4;
    #pragma unroll
    for (int j = 0; j < 4; ++j) {
      int n = n0 + cb + j * 4;
      float4 v = (n < N) ? *(const float4*)(W + (size_t)(k0 + r) * N + n)
                         : make_float4(0.f, 0.f, 0.f, 0.f);
      *(float4*)&tile[r][cb + j * 4] = v;
    }
  }
  __syncthreads();
  const int n = tid >> 2, ks = (tid & 3) << 4;
  u16x8 o0, o1;
  #pragma unroll
  for (int j = 0; j < 8; ++j) o0[j] = f2bf(tile[ks + j][n]);
  #pragma unroll
  for (int j = 0; j < 8; ++j) o1[j] = f2bf(tile[ks + 8 + j][n]);
  u16* dst = Wt + (size_t)(n0 + n) * K + k0 + ks;
  *(u16x8*)dst = o0;
  *(u16x8*)(dst + 8) = o1;
}

// ---------- GEMM 128x128 (2-phase) with split-K slabs ----------
// blockIdx.z = k-slice; slice does nkt k-tiles starting at z*nkt; C slab z.
__global__ __launch_bounds__(256) void gemm_bt(const u16* __restrict__ A,
                                               const u16* __restrict__ Bt,
                                               float* __restrict__ C,
                                               int M, int N, int K, int nkt) {
  __shared__ u16 As[128 * 64];
  __shared__ u16 Bs[128 * 64];
  const int tid = threadIdx.x;
  const int lane = tid & 63, w = tid >> 6;
  const int n0 = blockIdx.x << 7, m0 = blockIdx.y << 7;
  const int kt0 = blockIdx.z * nkt;
  float* Cs = C + (size_t)blockIdx.z * M * N;
  const int wr = w >> 1, wc = w & 1;
  const int lr = lane & 15, lg = lane >> 4;
  f32x4 acc[4][4] = {};
  const char* Ab = (const char*)A;
  const char* Bb = (const char*)Bt;
  const int stageOff = (w << 10) + (lane << 4);
  for (int kt = 0; kt < nkt; ++kt) {
    __syncthreads();
    const size_t kb = (size_t)(kt0 + kt) << 7;
    #pragma unroll
    for (int o = 0; o < 16384; o += 4096) {
      int ofs = stageOff + o;
      int row = ofs >> 7;
      int cb  = ofs & 127;
      gl16(Ab + (size_t)(m0 + row) * K * 2 + kb + cb, (char*)As + ofs);
      gl16(Bb + (size_t)(n0 + row) * K * 2 + kb + cb, (char*)Bs + ofs);
    }
    __syncthreads();
    bf16x8 a[4][2], b[4][2];
    #pragma unroll
    for (int m = 0; m < 4; ++m)
      #pragma unroll
      for (int kf = 0; kf < 2; ++kf)
        a[m][kf] = *(const bf16x8*)(As + ((wr * 64 + m * 16 + lr) * 64 + kf * 32 + lg * 8));
    #pragma unroll
    for (int n = 0; n < 4; ++n)
      #pragma unroll
      for (int kf = 0; kf < 2; ++kf)
        b[n][kf] = *(const bf16x8*)(Bs + ((wc * 64 + n * 16 + lr) * 64 + kf * 32 + lg * 8));
    #pragma unroll
    for (int kf = 0; kf < 2; ++kf)
      #pragma unroll
      for (int m = 0; m < 4; ++m)
        #pragma unroll
        for (int n = 0; n < 4; ++n)
          acc[m][n] = __builtin_amdgcn_mfma_f32_16x16x32_bf16(a[m][kf], b[n][kf], acc[m][n], 0, 0, 0);
  }
  #pragma unroll
  for (int m = 0; m < 4; ++m) {
    const int row0 = m0 + wr * 64 + m * 16 + lg * 4;
    #pragma unroll
    for (int n = 0; n < 4; ++n) {
      const int col = n0 + wc * 64 + n * 16 + lr;
      #pragma unroll
      for (int r = 0; r < 4; ++r)
        Cs[(size_t)(row0 + r) * N + col] = acc[m][n][r];
    }
  }
}

// ---------- GEMM 256x256, BK=64, 8 waves, 8-phase counted-vmcnt ----------
__global__ __launch_bounds__(512, 2) void gemm_bt_8ph(const u16* __restrict__ A,
                                                      const u16* __restrict__ Bt,
                                                      float* __restrict__ C,
                                                      int M, int N, int K) {
  __shared__ char lds[131072];
  const int nkt = K >> 6;
  const int tid = threadIdx.x;
  const int lane = tid & 63, wid = tid >> 6;
  const int wr = wid >> 2, wc = wid & 3;
  const int lr = lane & 15, lg = lane >> 4;

  const int nbx = N >> 8, nby = M >> 8;
  const int nwg = nbx * nby;
  const int wg  = blockIdx.x;
  const int swz = ((nwg & 7) == 0) ? ((wg & 7) * (nwg >> 3) + (wg >> 3)) : wg;
  const int bx = swz % nbx, by = swz / nbx;
  const int m0 = by << 8, n0 = bx << 8;

  const size_t rs = (size_t)K << 1;
  const char* Ab = (const char*)A;
  const char* Bb = (const char*)Bt;

  const int sofs = tid << 4;
  const int srow = sofs >> 7;
  const int scol = ((((sofs >> 4) & 7) ^ (srow & 7)) << 4);

  const int axor = lr & 7;
  const int sx0 = (lg ^ axor) << 4;
  const int sx1 = ((4 | lg) ^ axor) << 4;
  const int bcolbase = (wc & 1) << 13;

  f32x4 acc[8][4] = {};

#define ASL(p,h) ((((p) << 1) | (h)) << 14)
#define BSL(p,h) (65536 + ((((p) << 1) | (h)) << 14))
#define STAGE_HALF(gb, grow0, kt, slot)                                              \
  { const char* _s = (gb) + (size_t)(grow0) * rs + ((size_t)(kt) << 7) + scol;       \
    gl16(_s, lds + (slot) + sofs);                                                   \
    gl16(_s + (rs << 6), lds + (slot) + sofs + 8192); }

  STAGE_HALF(Ab, m0 + srow,       0, ASL(0,0));
  STAGE_HALF(Ab, m0 + 128 + srow, 0, ASL(0,1));
  STAGE_HALF(Bb, n0 + srow,       0, BSL(0,0));
  STAGE_HALF(Bb, n0 + 128 + srow, 0, BSL(0,1));
  if (nkt > 1) {
    STAGE_HALF(Bb, n0 + srow,       1, BSL(1,0));
    STAGE_HALF(Bb, n0 + 128 + srow, 1, BSL(1,1));
    WAITVM4;
  } else {
    WAITVM0;
  }
  BAR();

  for (int b = 0; b < nkt; ++b) {
    const int p = b & 1;
    const int abase = ASL(p, wr);
    const int bbase = BSL(p, (wc >> 1)) + bcolbase;
    bf16x8 aR[4][2], bR[4][2];

    #pragma unroll
    for (int m = 0; m < 4; ++m) {
      aR[m][0] = *(const bf16x8*)(lds + abase + (m * 16 + lr) * 128 + sx0);
      aR[m][1] = *(const bf16x8*)(lds + abase + (m * 16 + lr) * 128 + sx1);
    }
    #pragma unroll
    for (int n = 0; n < 2; ++n) {
      bR[n][0] = *(const bf16x8*)(lds + bbase + (n * 16 + lr) * 128 + sx0);
      bR[n][1] = *(const bf16x8*)(lds + bbase + (n * 16 + lr) * 128 + sx1);
    }
    if (b + 1 < nkt) { STAGE_HALF(Ab, m0 + srow, b + 1, ASL((b + 1) & 1, 0)); }
    BAR(); WAITLG0; SCHEDB();
    __builtin_amdgcn_s_setprio(1);
    #pragma unroll
    for (int kf = 0; kf < 2; ++kf)
      #pragma unroll
      for (int m = 0; m < 4; ++m)
        #pragma unroll
        for (int n = 0; n < 2; ++n)
          acc[m][n] = __builtin_amdgcn_mfma_f32_16x16x32_bf16(aR[m][kf], bR[n][kf], acc[m][n], 0, 0, 0);
    __builtin_amdgcn_s_setprio(0); SCHEDB();
    BAR();

    #pragma unroll
    for (int n = 2; n < 4; ++n) {
      bR[n][0] = *(const bf16x8*)(lds + bbase + (n * 16 + lr) * 128 + sx0);
      bR[n][1] = *(const bf16x8*)(lds + bbase + (n * 16 + lr) * 128 + sx1);
    }
    if (b + 1 < nkt) { STAGE_HALF(Ab, m0 + 128 + srow, b + 1, ASL((b + 1) & 1, 1)); }
    BAR(); WAITLG0; SCHEDB();
    __builtin_amdgcn_s_setprio(1);
    #pragma unroll
    for (int kf = 0; kf < 2; ++kf)
      #pragma unroll
      for (int m = 0; m < 4; ++m)
        #pragma unroll
        for (int n = 2; n < 4; ++n)
          acc[m][n] = __builtin_amdgcn_mfma_f32_16x16x32_bf16(aR[m][kf], bR[n][kf], acc[m][n], 0, 0, 0);
    __builtin_amdgcn_s_setprio(0); SCHEDB();
    BAR();

    #pragma unroll
    for (int m = 0; m < 4; ++m) {
      aR[m][0] = *(const bf16x8*)(lds + abase + ((m + 4) * 16 + lr) * 128 + sx0);
      aR[m][1] = *(const bf16x8*)(lds + abase + ((m + 4) * 16 + lr) * 128 + sx1);
    }
    if (b + 2 < nkt) { STAGE_HALF(Bb, n0 + srow, b + 2, BSL(p, 0)); }
    BAR(); WAITLG0; SCHEDB();
    __builtin_amdgcn_s_setprio(1);
    #pragma unroll
    for (int kf = 0; kf < 2; ++kf)
      #pragma unroll
      for (int m = 0; m < 4; ++m)
        #pragma unroll
        for (int n = 0; n < 2; ++n)
          acc[m + 4][n] = __builtin_amdgcn_mfma_f32_16x16x32_bf16(aR[m][kf], bR[n][kf], acc[m + 4][n], 0, 0, 0);
    __builtin_amdgcn_s_setprio(0); SCHEDB();
    BAR();

    if (b + 2 < nkt) { STAGE_HALF(Bb, n0 + 128 + srow, b + 2, BSL(p, 1)); }
    BAR(); SCHEDB();
    __builtin_amdgcn_s_setprio(1);
    #pragma unroll
    for (int kf = 0; kf < 2; ++kf)
      #pragma unroll
      for (int m = 0; m < 4; ++m)
        #pragma unroll
        for (int n = 2; n < 4; ++n)
          acc[m + 4][n] = __builtin_amdgcn_mfma_f32_16x16x32_bf16(aR[m][kf], bR[n][kf], acc[m + 4][n], 0, 0, 0);
    __builtin_amdgcn_s_setprio(0); SCHEDB();
    if (b + 2 < nkt) { WAITVM4; } else { WAITVM0; }
    BAR();
  }

  #pragma unroll
  for (int m = 0; m < 8; ++m) {
    const int row0 = m0 + wr * 128 + m * 16 + lg * 4;
    #pragma unroll
    for (int n = 0; n < 4; ++n) {
      const int col = n0 + wc * 64 + n * 16 + lr;
      #pragma unroll
      for (int r = 0; r < 4; ++r)
        C[(size_t)(row0 + r) * N + col] = acc[m][n][r];
    }
  }
#undef ASL
#undef BSL
#undef STAGE_HALF
}

// ---------- RMSNorm q: sums 4 split-K slabs, then normalizes ----------
#define SLAB ((size_t)2048 * 2176)
__global__ __launch_bounds__(256) void norm_q_kernel(const float* __restrict__ x,
                                                     const float* __restrict__ w,
                                                     u16* __restrict__ y) {
  const int row = blockIdx.x, tid = threadIdx.x;
  const float* xr = x + (size_t)row * 2176;
  float v[6]; float ss = 0.f;
  #pragma unroll
  for (int i = 0; i < 6; ++i) {
    size_t o = tid + i * 256;
    v[i] = xr[o] + xr[o + SLAB] + xr[o + 2 * SLAB] + xr[o + 3 * SLAB];
    ss += v[i] * v[i];
  }
  __shared__ float sm[4];
  #pragma unroll
  for (int o = 32; o > 0; o >>= 1) ss += __shfl_down(ss, o, 64);
  if ((tid & 63) == 0) sm[tid >> 6] = ss;
  __syncthreads();
  float tot = sm[0] + sm[1] + sm[2] + sm[3];
  float rs = rsqrtf(tot * (1.f / 1536.f) + 1e-6f);
  #pragma unroll
  for (int i = 0; i < 6; ++i)
    y[(size_t)row * 1536 + tid + i * 256] = f2bf(v[i] * rs * w[tid + i * 256]);
}

// ---------- RMSNorm kv + RoPE(k): sums 4 slabs ----------
__global__ __launch_bounds__(256) void norm_kv_kernel(const float* __restrict__ kva,
                                                      const float* __restrict__ w,
                                                      const int* __restrict__ pos,
                                                      u16* __restrict__ comp,
                                                      u16* __restrict__ krope) {
  const int row = blockIdx.x, tid = threadIdx.x;
  const float* xr = kva + (size_t)row * 2176 + 1536;
  float v0 = xr[tid] + xr[tid + SLAB] + xr[tid + 2 * SLAB] + xr[tid + 3 * SLAB];
  size_t o1 = tid + 256;
  float v1 = xr[o1] + xr[o1 + SLAB] + xr[o1 + 2 * SLAB] + xr[o1 + 3 * SLAB];
  float ss = v0 * v0 + v1 * v1;
  __shared__ float sm[4];
  #pragma unroll
  for (int o = 32; o > 0; o >>= 1) ss += __shfl_down(ss, o, 64);
  if ((tid & 63) == 0) sm[tid >> 6] = ss;
  __syncthreads();
  float tot = sm[0] + sm[1] + sm[2] + sm[3];
  float rs = rsqrtf(tot * (1.f / 512.f) + 1e-6f);
  comp[(size_t)row * 512 + tid]       = f2bf(v0 * rs * w[tid]);
  comp[(size_t)row * 512 + tid + 256] = f2bf(v1 * rs * w[tid + 256]);
  if (tid < 32) {
    float p = (float)pos[row];
    float inv = powf(10000.0f, -(float)(2 * tid) * (1.0f / 64.0f));
    float ang = p * inv;
    float c = cosf(ang), s = sinf(ang);
    size_t e1 = 512 + 2 * tid, e2 = e1 + 1;
    float x1 = xr[e1] + xr[e1 + SLAB] + xr[e1 + 2 * SLAB] + xr[e1 + 3 * SLAB];
    float x2 = xr[e2] + xr[e2 + SLAB] + xr[e2 + 2 * SLAB] + xr[e2 + 3 * SLAB];
    krope[(size_t)row * 64 + 2 * tid]     = f2bf(x1 * c - x2 * s);
    krope[(size_t)row * 64 + 2 * tid + 1] = f2bf(x1 * s + x2 * c);
  }
}

// ---------- RoPE(q) + relayout q_all[h][t][192] ----------
__global__ __launch_bounds__(256) void rope_q_kernel(const float* __restrict__ qb,
                                                     const int* __restrict__ pos,
                                                     u16* __restrict__ q_all) {
  const int t = blockIdx.x, tid = threadIdx.x;
  const float* qr = qb + (size_t)t * 6144;
  const float p = (float)pos[t];
  for (int idx = tid; idx < 4096; idx += 256) {
    int h = idx >> 7, d = idx & 127;
    q_all[((size_t)h * 2048 + t) * 192 + d] = f2bf(qr[h * 192 + d]);
  }
  for (int idx = tid; idx < 1024; idx += 256) {
    int h = idx >> 5, i = idx & 31;
    float inv = powf(10000.0f, -(float)(2 * i) * (1.0f / 64.0f));
    float ang = p * inv;
    float c = cosf(ang), s = sinf(ang);
    float x1 = qr[h * 192 + 128 + 2 * i], x2 = qr[h * 192 + 128 + 2 * i + 1];
    size_t ob = ((size_t)h * 2048 + t) * 192 + 128;
    q_all[ob + 2 * i]     = f2bf(x1 * c - x2 * s);
    q_all[ob + 2 * i + 1] = f2bf(x1 * s + x2 * c);
  }
}

// ---------- split kv -> k_all[h][s][200], v_t[h][d][2048] ----------
__global__ __launch_bounds__(256) void kvsplit_kernel(const float* __restrict__ kv,
                                                      const u16* __restrict__ krope,
                                                      u16* __restrict__ k_all,
                                                      u16* __restrict__ v_t) {
  const int h = blockIdx.x & 31, st = blockIdx.x >> 5, tid = threadIdx.x;
  const int s0 = st * 64;
  for (int idx = tid; idx < 8192; idx += 256) {
    int s = idx >> 7, d = idx & 127;
    k_all[((size_t)h * 2048 + s0 + s) * 200 + d] =
        f2bf(kv[(size_t)(s0 + s) * 8192 + h * 256 + d]);
  }
  for (int idx = tid; idx < 4096; idx += 256) {
    int s = idx >> 6, j = idx & 63;
    k_all[((size_t)h * 2048 + s0 + s) * 200 + 128 + j] = krope[(size_t)(s0 + s) * 64 + j];
  }
  __shared__ u16 vs[64][128];
  for (int idx = tid; idx < 8192; idx += 256) {
    int s = idx >> 7, d = idx & 127;
    vs[s][d] = f2bf(kv[(size_t)(s0 + s) * 8192 + h * 256 + 128 + d]);
  }
  __syncthreads();
  const int d = tid >> 1, sh = (tid & 1) * 32;
  u16 tmp[32];
  #pragma unroll
  for (int i = 0; i < 32; ++i) tmp[i] = vs[sh + i][d];
  #pragma unroll
  for (int b = 0; b < 4; ++b) {
    u16x8 o;
    #pragma unroll
    for (int j = 0; j < 8; ++j) o[j] = tmp[b * 8 + j];
    *(u16x8*)(v_t + ((size_t)h * 128 + d) * 2048 + s0 + sh + b * 8) = o;
  }
}

// ---------- flash attention: 8 waves, 128q x 64s tiles, dbuf, swapped-QK ----------
#define SCL2 0.10412706f
#define THR2 11.5f
__global__ __launch_bounds__(512, 2) void attn_fwd(const u16* __restrict__ q_all,
                                                   const u16* __restrict__ k_all,
                                                   const u16* __restrict__ v_t,
                                                   u16* __restrict__ attnb) {
  __shared__ __align__(16) char lds[106496];
  const int tid = threadIdx.x;
  const int lane = tid & 63, wid = tid >> 6;
  const int lr = lane & 15, lg = lane >> 4;
  const int h = blockIdx.x & 31, bq = blockIdx.x >> 5;

  const char* kh = (const char*)(k_all + (size_t)h * 2048 * 200);
  const char* vh = (const char*)(v_t + (size_t)h * 128 * 2048);
  char* Pw = lds + 88064 + wid * 2304;

  const int nCalls = (wid < 3) ? 6 : 5;
  const char* gp[6]; int cofs[6]; int isK[6];
  #pragma unroll
  for (int ii = 0; ii < 6; ++ii) {
    int i = wid + (ii << 3);
    if (i < 43) {
      int c = (i << 6) + lane;
      cofs[ii] = c << 4;
      if (c < 1600) { gp[ii] = kh + ((size_t)c << 4); isK[ii] = 1; }
      else {
        int cv = c - 1600;
        int row = cv / 9, sub = cv - row * 9;
        gp[ii] = vh + ((size_t)row << 12) + ((sub < 8) ? (sub << 4) : 0);
        isK[ii] = 0;
      }
    } else { gp[ii] = kh; cofs[ii] = 0; isK[ii] = 1; }
  }

#define STAGE(s0_, bOff_)                                                       \
  { int _sk = (s0_) * 400, _sv = (s0_) * 2;                                     \
    _Pragma("unroll")                                                           \
    for (int ii = 0; ii < 6; ++ii)                                              \
      if (ii < nCalls)                                                          \
        gl16(gp[ii] + (isK[ii] ? _sk : _sv), lds + (bOff_) + cofs[ii]); }

#define WAITSTAGE                                                               \
  { if (wid < 3) { asm volatile("s_waitcnt vmcnt(6)" ::: "memory"); }           \
    else        { asm volatile("s_waitcnt vmcnt(5)" ::: "memory"); } }

  const int kRd = lr * 400 + lg * 16;
  const int vRd = lr * 144 + lg * 16;
  const int pRd = lr * 144 + lg * 16;
  const int pWr = lr * 144 + lg * 8;

  #pragma unroll
  for (int half = 0; half < 2; ++half) {
    const int qt = half ? (15 - bq) : bq;
    const int qb0 = qt << 7;
    const int nt = 2 * qt + 2;
    const int qlane = qb0 + wid * 16 + lr;
    const int qwmin = qb0 + wid * 16;

    bf16x8 qf[6];
    const u16* qptr = q_all + ((size_t)h * 2048 + qlane) * 192 + lg * 8;
    #pragma unroll
    for (int kf = 0; kf < 6; ++kf) qf[kf] = *(const bf16x8*)(qptr + kf * 32);

    f32x4 O[8] = {};
    float m = -1e30f, l = 0.f;

    STAGE(0, 0);
    for (int st = 0; st < nt; ++st) {
      const int s0 = st << 6;
      const int bOff = (st & 1) * 44032;
      if (st + 1 < nt) {
        STAGE((st + 1) << 6, ((st + 1) & 1) * 44032);
        WAITSTAGE;
      } else {
        WAITVM0;
      }
      BAR();

      const bool active = (s0 <= qwmin + 15);
      if (active) {
        const char* Kb = lds + bOff;
        const char* Vb = lds + bOff + 25600;

        f32x4 S[4];
        #pragma unroll
        for (int sb = 0; sb < 4; ++sb) {
          f32x4 a = {};
          #pragma unroll
          for (int kf = 0; kf < 6; ++kf) {
            bf16x8 kfr = *(const bf16x8*)(Kb + kRd + sb * 6400 + kf * 64);
            a = __builtin_amdgcn_mfma_f32_16x16x32_bf16(kfr, qf[kf], a, 0, 0, 0);
          }
          S[sb] = a;
        }

        if (s0 + 63 > qwmin) {
          const int kb0 = s0 + lg * 4;
          #pragma unroll
          for (int sb = 0; sb < 4; ++sb)
            #pragma unroll
            for (int r = 0; r < 4; ++r) {
              int k = kb0 + sb * 16 + r;
              S[sb][r] = (k > qlane) ? -1e30f : S[sb][r] * SCL2;
            }
        } else {
          #pragma unroll
          for (int sb = 0; sb < 4; ++sb)
            #pragma unroll
            for (int r = 0; r < 4; ++r) S[sb][r] *= SCL2;
        }

        float mx = S[0][0];
        #pragma unroll
        for (int sb = 0; sb < 4; ++sb)
          #pragma unroll
          for (int r = 0; r < 4; ++r) mx = fmaxf(mx, S[sb][r]);
        mx = fmaxf(mx, __shfl_xor(mx, 16, 64));
        mx = fmaxf(mx, __shfl_xor(mx, 32, 64));

        const bool skip = __all(mx <= m + THR2);
        float alpha = 1.f;
        if (!skip) { float mn = fmaxf(m, mx); alpha = exp2f(m - mn); m = mn; }

        float ps = 0.f;
        #pragma unroll
        for (int sb = 0; sb < 4; ++sb)
          #pragma unroll
          for (int r = 0; r < 4; ++r) {
            float pv = exp2f(S[sb][r] - m);
            S[sb][r] = pv;
            ps += pv;
          }
        ps += __shfl_xor(ps, 16, 64);
        ps += __shfl_xor(ps, 32, 64);
        l = l * alpha + ps;

        if (!skip) {
          float aO[4];
          #pragma unroll
          for (int r = 0; r < 4; ++r) aO[r] = __shfl(alpha, lg * 4 + r, 64);
          #pragma unroll
          for (int nb = 0; nb < 8; ++nb)
            #pragma unroll
            for (int r = 0; r < 4; ++r) O[nb][r] *= aO[r];
        }

        #pragma unroll
        for (int sb = 0; sb < 4; ++sb) {
          u32 p01, p23;
          asm("v_cvt_pk_bf16_f32 %0, %1, %2" : "=v"(p01) : "v"(S[sb][0]), "v"(S[sb][1]));
          asm("v_cvt_pk_bf16_f32 %0, %1, %2" : "=v"(p23) : "v"(S[sb][2]), "v"(S[sb][3]));
          *(uint2*)(Pw + pWr + sb * 32) = make_uint2(p01, p23);
        }

        #pragma unroll
        for (int k2 = 0; k2 < 2; ++k2) {
          bf16x8 pa = *(const bf16x8*)(Pw + pRd + k2 * 64);
          #pragma unroll
          for (int nb = 0; nb < 8; ++nb) {
            bf16x8 vf = *(const bf16x8*)(Vb + vRd + nb * 2304 + k2 * 64);
            O[nb] = __builtin_amdgcn_mfma_f32_16x16x32_bf16(pa, vf, O[nb], 0, 0, 0);
          }
        }
      }
      BAR();
    }

    float rv[4];
    #pragma unroll
    for (int r = 0; r < 4; ++r) rv[r] = 1.f / __shfl(l, lg * 4 + r, 64);
    #pragma unroll
    for (int nb = 0; nb < 8; ++nb) {
      const int col = h * 128 + nb * 16 + lr;
      #pragma unroll
      for (int r = 0; r < 4; ++r)
        attnb[(size_t)(qb0 + wid * 16 + lg * 4 + r) * 4096 + col] = f2bf(O[nb][r] * rv[r]);
    }
  }
#undef STAGE
#undef WAITSTAGE
}

// ---------- host ----------
extern "C" void kernel_launch(void* const* d_in, const int* in_sizes, int n_in,
                              void* d_out, int out_size, void* d_ws, size_t ws_size,
                              hipStream_t stream) {
  const int*   positions = (const int*)d_in[0];
  const float* hidden    = (const float*)d_in[1];
  const float* w_q_a     = (const float*)d_in[2];
  const float* q_a_norm  = (const float*)d_in[3];
  const float* w_q_b     = (const float*)d_in[4];
  const float* w_kv_a    = (const float*)d_in[5];
  const float* kv_a_norm = (const float*)d_in[6];
  const float* w_kv_b    = (const float*)d_in[7];
  const float* w_o       = (const float*)d_in[8];
  float* out = (float*)d_out;
  char*  ws  = (char*)d_ws;

  // layout (bytes): hs_bf 0..21M | Wt 21..63M | Creg 63..134.2M (slabs / q_big /
  // kv_big / attnb) | q_c_n | comp | krope | q_all | k_all | v_t  (end 211.0M)
  u16* hs_bf  = (u16*)(ws + 0);
  u16* Wt     = (u16*)(ws + 20971520);
  char* Creg  = ws + 62914560;                 // 71,303,168-byte region
  float* slabs   = (float*)Creg;               // 4 x 2048x2176 f32
  float* q_big   = (float*)Creg;
  float* kv_big  = (float*)Creg;
  u16*   attnb   = (u16*)Creg;
  u16* q_c_n  = (u16*)(ws + 134217728);
  u16* comp   = (u16*)(ws + 140509184);
  u16* krope  = (u16*)(ws + 142606336);
  u16* q_all  = (u16*)(ws + 142868480);
  u16* k_all  = (u16*)(ws + 168034304);
  u16* v_t    = (u16*)(ws + 194248704);

  u16* wqa_t  = Wt;
  u16* wkva_t = Wt + (size_t)1536 * 5120;

  cvt_f32_bf16<<<2048, 256, 0, stream>>>(hidden, hs_bf, (2048 * 5120) / 4);
  transpose_w<<<dim3(24, 80), 256, 0, stream>>>(w_q_a,  wqa_t,  5120, 1536, 1536);
  transpose_w<<<dim3(10, 80), 256, 0, stream>>>(w_kv_a, wkva_t, 5120, 576,  640);

  // merged LoRA-A GEMM, split-K=4 into slabs
  gemm_bt<<<dim3(17, 16, 4), 256, 0, stream>>>(hs_bf, wqa_t, slabs, 2048, 2176, 5120, 20);

  // norms fuse the 4-slab reduction
  norm_q_kernel<<<2048, 256, 0, stream>>>(slabs, q_a_norm, q_c_n);
  norm_kv_kernel<<<2048, 256, 0, stream>>>(slabs, kv_a_norm, positions, comp, krope);

  transpose_w<<<dim3(96, 24), 256, 0, stream>>>(w_q_b, Wt, 1536, 6144, 6144);
  gemm_bt_8ph<<<192, 512, 0, stream>>>(q_c_n, Wt, q_big, 2048, 6144, 1536);
  rope_q_kernel<<<2048, 256, 0, stream>>>(q_big, positions, q_all);

  transpose_w<<<dim3(128, 8), 256, 0, stream>>>(w_kv_b, Wt, 512, 8192, 8192);
  gemm_bt_8ph<<<256, 512, 0, stream>>>(comp, Wt, kv_big, 2048, 8192, 512);
  kvsplit_kernel<<<1024, 256, 0, stream>>>(kv_big, krope, k_all, v_t);

  transpose_w<<<dim3(80, 64), 256, 0, stream>>>(w_o, Wt, 4096, 5120, 5120);
  attn_fwd<<<256, 512, 0, stream>>>(q_all, k_all, v_t, attnb);

  gemm_bt_8ph<<<160, 512, 0, stream>>>(attnb, Wt, out, 2048, 5120, 4096);
}

// Round 5
// 477.037 us; speedup vs baseline: 1.5955x; 1.1172x over previous
//
#include <hip/hip_runtime.h>

typedef unsigned short u16;
typedef unsigned int   u32;
typedef __bf16 bf16x8 __attribute__((ext_vector_type(8)));
typedef float  f32x4  __attribute__((ext_vector_type(4)));
typedef u16    u16x4  __attribute__((ext_vector_type(4)));
typedef u16    u16x8  __attribute__((ext_vector_type(8)));

// ---------- helpers ----------
__device__ __forceinline__ u16 f2bf(float f) {
  u32 u = __float_as_uint(f);
  u32 r = u + 0x7fffu + ((u >> 16) & 1u);   // RTNE
  return (u16)(r >> 16);
}
__device__ __forceinline__ float b2f(u16 v) {
  u32 u = (u32)v << 16;
  return __uint_as_float(u);
}

__device__ __forceinline__ void gl16(const void* g, void* l) {
  __builtin_amdgcn_global_load_lds((__attribute__((address_space(1))) void*)(g),
                                   (__attribute__((address_space(3))) void*)(l),
                                   16, 0, 0);
}

#define WAITVM4  asm volatile("s_waitcnt vmcnt(4)" ::: "memory")
#define WAITVM0  asm volatile("s_waitcnt vmcnt(0)" ::: "memory")
#define WAITLG0  asm volatile("s_waitcnt lgkmcnt(0)" ::: "memory")
#define BAR()    asm volatile("s_barrier" ::: "memory")
#define SCHEDB() __builtin_amdgcn_sched_barrier(0)

// ---------- fp32 -> bf16 elementwise ----------
__global__ __launch_bounds__(256) void cvt_f32_bf16(const float* __restrict__ x,
                                                    u16* __restrict__ y, int n4) {
  for (int i = blockIdx.x * 256 + threadIdx.x; i < n4; i += gridDim.x * 256) {
    float4 v = ((const float4*)x)[i];
    u16x4 o;
    o[0] = f2bf(v.x); o[1] = f2bf(v.y); o[2] = f2bf(v.z); o[3] = f2bf(v.w);
    ((u16x4*)y)[i] = o;
  }
}

// ---------- transpose+convert: W[K][N] fp32 -> Wt[Npad][K] bf16 (32x32, proven) ----------
__global__ __launch_bounds__(256) void transpose_w(const float* __restrict__ W,
                                                   u16* __restrict__ Wt,
                                                   int K, int N, int Npad) {
  __shared__ float tile[32][33];
  const int n0 = blockIdx.x * 32, k0 = blockIdx.y * 32;
  const int tid = threadIdx.x;
  const int r  = tid >> 3;
  const int c4 = (tid & 7) << 2;
  float4 v = make_float4(0.f, 0.f, 0.f, 0.f);
  if (n0 + c4 < N) v = *(const float4*)(W + (size_t)(k0 + r) * N + n0 + c4);
  tile[r][c4 + 0] = v.x; tile[r][c4 + 1] = v.y;
  tile[r][c4 + 2] = v.z; tile[r][c4 + 3] = v.w;
  __syncthreads();
  u16x4 o;
  o[0] = f2bf(tile[c4 + 0][r]); o[1] = f2bf(tile[c4 + 1][r]);
  o[2] = f2bf(tile[c4 + 2][r]); o[3] = f2bf(tile[c4 + 3][r]);
  *(u16x4*)(Wt + (size_t)(n0 + r) * K + k0 + c4) = o;
}

// ---------- LoRA-A GEMM 128x128 (2-phase) with split-K slabs ----------
__global__ __launch_bounds__(256) void gemm_a(const u16* __restrict__ A,
                                              const u16* __restrict__ Bt,
                                              float* __restrict__ C,
                                              int M, int N, int K, int nkt) {
  __shared__ u16 As[128 * 64];
  __shared__ u16 Bs[128 * 64];
  const int tid = threadIdx.x;
  const int lane = tid & 63, w = tid >> 6;
  const int n0 = blockIdx.x << 7, m0 = blockIdx.y << 7;
  const int kt0 = blockIdx.z * nkt;
  float* Cs = C + (size_t)blockIdx.z * M * N;
  const int wr = w >> 1, wc = w & 1;
  const int lr = lane & 15, lg = lane >> 4;
  f32x4 acc[4][4] = {};
  const char* Ab = (const char*)A;
  const char* Bb = (const char*)Bt;
  const int stageOff = (w << 10) + (lane << 4);
  for (int kt = 0; kt < nkt; ++kt) {
    __syncthreads();
    const size_t kb = (size_t)(kt0 + kt) << 7;
    #pragma unroll
    for (int o = 0; o < 16384; o += 4096) {
      int ofs = stageOff + o;
      int row = ofs >> 7;
      int cb  = ofs & 127;
      gl16(Ab + (size_t)(m0 + row) * K * 2 + kb + cb, (char*)As + ofs);
      gl16(Bb + (size_t)(n0 + row) * K * 2 + kb + cb, (char*)Bs + ofs);
    }
    __syncthreads();
    bf16x8 a[4][2], b[4][2];
    #pragma unroll
    for (int m = 0; m < 4; ++m)
      #pragma unroll
      for (int kf = 0; kf < 2; ++kf)
        a[m][kf] = *(const bf16x8*)(As + ((wr * 64 + m * 16 + lr) * 64 + kf * 32 + lg * 8));
    #pragma unroll
    for (int n = 0; n < 4; ++n)
      #pragma unroll
      for (int kf = 0; kf < 2; ++kf)
        b[n][kf] = *(const bf16x8*)(Bs + ((wc * 64 + n * 16 + lr) * 64 + kf * 32 + lg * 8));
    #pragma unroll
    for (int kf = 0; kf < 2; ++kf)
      #pragma unroll
      for (int m = 0; m < 4; ++m)
        #pragma unroll
        for (int n = 0; n < 4; ++n)
          acc[m][n] = __builtin_amdgcn_mfma_f32_16x16x32_bf16(a[m][kf], b[n][kf], acc[m][n], 0, 0, 0);
  }
  #pragma unroll
  for (int m = 0; m < 4; ++m) {
    const int row0 = m0 + wr * 64 + m * 16 + lg * 4;
    #pragma unroll
    for (int n = 0; n < 4; ++n) {
      const int col = n0 + wc * 64 + n * 16 + lr;
      #pragma unroll
      for (int r = 0; r < 4; ++r)
        Cs[(size_t)(row0 + r) * N + col] = acc[m][n][r];
    }
  }
}

// ---------- shared 8-phase 256x256 GEMM body (BK=64, 8 waves, counted vmcnt) ----------
template<int BF16OUT>
__device__ __forceinline__ void gemm8_body(char* lds,
                                           const u16* __restrict__ A,
                                           const u16* __restrict__ Bt,
                                           void* __restrict__ Cv,
                                           int N, int K, int wg, int nwg, int nbx) {
  const int nkt = K >> 6;
  const int tid = threadIdx.x;
  const int lane = tid & 63, wid = tid >> 6;
  const int wr = wid >> 2, wc = wid & 3;
  const int lr = lane & 15, lg = lane >> 4;

  const int swz = ((nwg & 7) == 0) ? ((wg & 7) * (nwg >> 3) + (wg >> 3)) : wg;
  const int bx = swz % nbx, by = swz / nbx;
  const int m0 = by << 8, n0 = bx << 8;

  const size_t rs = (size_t)K << 1;
  const char* Ab = (const char*)A;
  const char* Bb = (const char*)Bt;

  const int sofs = tid << 4;
  const int srow = sofs >> 7;
  const int scol = ((((sofs >> 4) & 7) ^ (srow & 7)) << 4);

  const int axor = lr & 7;
  const int sx0 = (lg ^ axor) << 4;
  const int sx1 = ((4 | lg) ^ axor) << 4;
  const int bcolbase = (wc & 1) << 13;

  f32x4 acc[8][4] = {};

#define ASL(p,h) ((((p) << 1) | (h)) << 14)
#define BSL(p,h) (65536 + ((((p) << 1) | (h)) << 14))
#define STAGE_HALF(gb, grow0, kt, slot)                                              \
  { const char* _s = (gb) + (size_t)(grow0) * rs + ((size_t)(kt) << 7) + scol;       \
    gl16(_s, lds + (slot) + sofs);                                                   \
    gl16(_s + (rs << 6), lds + (slot) + sofs + 8192); }

  STAGE_HALF(Ab, m0 + srow,       0, ASL(0,0));
  STAGE_HALF(Ab, m0 + 128 + srow, 0, ASL(0,1));
  STAGE_HALF(Bb, n0 + srow,       0, BSL(0,0));
  STAGE_HALF(Bb, n0 + 128 + srow, 0, BSL(0,1));
  if (nkt > 1) {
    STAGE_HALF(Bb, n0 + srow,       1, BSL(1,0));
    STAGE_HALF(Bb, n0 + 128 + srow, 1, BSL(1,1));
    WAITVM4;
  } else {
    WAITVM0;
  }
  BAR();

  for (int b = 0; b < nkt; ++b) {
    const int p = b & 1;
    const int abase = ASL(p, wr);
    const int bbase = BSL(p, (wc >> 1)) + bcolbase;
    bf16x8 aR[4][2], bR[4][2];

    #pragma unroll
    for (int m = 0; m < 4; ++m) {
      aR[m][0] = *(const bf16x8*)(lds + abase + (m * 16 + lr) * 128 + sx0);
      aR[m][1] = *(const bf16x8*)(lds + abase + (m * 16 + lr) * 128 + sx1);
    }
    #pragma unroll
    for (int n = 0; n < 2; ++n) {
      bR[n][0] = *(const bf16x8*)(lds + bbase + (n * 16 + lr) * 128 + sx0);
      bR[n][1] = *(const bf16x8*)(lds + bbase + (n * 16 + lr) * 128 + sx1);
    }
    if (b + 1 < nkt) { STAGE_HALF(Ab, m0 + srow, b + 1, ASL((b + 1) & 1, 0)); }
    BAR(); WAITLG0; SCHEDB();
    __builtin_amdgcn_s_setprio(1);
    #pragma unroll
    for (int kf = 0; kf < 2; ++kf)
      #pragma unroll
      for (int m = 0; m < 4; ++m)
        #pragma unroll
        for (int n = 0; n < 2; ++n)
          acc[m][n] = __builtin_amdgcn_mfma_f32_16x16x32_bf16(aR[m][kf], bR[n][kf], acc[m][n], 0, 0, 0);
    __builtin_amdgcn_s_setprio(0); SCHEDB();
    BAR();

    #pragma unroll
    for (int n = 2; n < 4; ++n) {
      bR[n][0] = *(const bf16x8*)(lds + bbase + (n * 16 + lr) * 128 + sx0);
      bR[n][1] = *(const bf16x8*)(lds + bbase + (n * 16 + lr) * 128 + sx1);
    }
    if (b + 1 < nkt) { STAGE_HALF(Ab, m0 + 128 + srow, b + 1, ASL((b + 1) & 1, 1)); }
    BAR(); WAITLG0; SCHEDB();
    __builtin_amdgcn_s_setprio(1);
    #pragma unroll
    for (int kf = 0; kf < 2; ++kf)
      #pragma unroll
      for (int m = 0; m < 4; ++m)
        #pragma unroll
        for (int n = 2; n < 4; ++n)
          acc[m][n] = __builtin_amdgcn_mfma_f32_16x16x32_bf16(aR[m][kf], bR[n][kf], acc[m][n], 0, 0, 0);
    __builtin_amdgcn_s_setprio(0); SCHEDB();
    BAR();

    #pragma unroll
    for (int m = 0; m < 4; ++m) {
      aR[m][0] = *(const bf16x8*)(lds + abase + ((m + 4) * 16 + lr) * 128 + sx0);
      aR[m][1] = *(const bf16x8*)(lds + abase + ((m + 4) * 16 + lr) * 128 + sx1);
    }
    if (b + 2 < nkt) { STAGE_HALF(Bb, n0 + srow, b + 2, BSL(p, 0)); }
    BAR(); WAITLG0; SCHEDB();
    __builtin_amdgcn_s_setprio(1);
    #pragma unroll
    for (int kf = 0; kf < 2; ++kf)
      #pragma unroll
      for (int m = 0; m < 4; ++m)
        #pragma unroll
        for (int n = 0; n < 2; ++n)
          acc[m + 4][n] = __builtin_amdgcn_mfma_f32_16x16x32_bf16(aR[m][kf], bR[n][kf], acc[m + 4][n], 0, 0, 0);
    __builtin_amdgcn_s_setprio(0); SCHEDB();
    BAR();

    if (b + 2 < nkt) { STAGE_HALF(Bb, n0 + 128 + srow, b + 2, BSL(p, 1)); }
    BAR(); SCHEDB();
    __builtin_amdgcn_s_setprio(1);
    #pragma unroll
    for (int kf = 0; kf < 2; ++kf)
      #pragma unroll
      for (int m = 0; m < 4; ++m)
        #pragma unroll
        for (int n = 2; n < 4; ++n)
          acc[m + 4][n] = __builtin_amdgcn_mfma_f32_16x16x32_bf16(aR[m][kf], bR[n][kf], acc[m + 4][n], 0, 0, 0);
    __builtin_amdgcn_s_setprio(0); SCHEDB();
    if (b + 2 < nkt) { WAITVM4; } else { WAITVM0; }
    BAR();
  }

  #pragma unroll
  for (int m = 0; m < 8; ++m) {
    const int row0 = m0 + wr * 128 + m * 16 + lg * 4;
    #pragma unroll
    for (int n = 0; n < 4; ++n) {
      const int col = n0 + wc * 64 + n * 16 + lr;
      #pragma unroll
      for (int r = 0; r < 4; ++r) {
        if (BF16OUT) ((u16*)Cv)[(size_t)(row0 + r) * N + col] = f2bf(acc[m][n][r]);
        else         ((float*)Cv)[(size_t)(row0 + r) * N + col] = acc[m][n][r];
      }
    }
  }
#undef ASL
#undef BSL
#undef STAGE_HALF
}

// ---------- fused q_b + kv_b launch (union grid: 192 q-blocks then 256 kv-blocks) ----------
__global__ __launch_bounds__(512, 2) void gemm_fused_b(const u16* __restrict__ A1,
                                                       const u16* __restrict__ B1,
                                                       u16* __restrict__ C1,
                                                       const u16* __restrict__ A2,
                                                       const u16* __restrict__ B2,
                                                       u16* __restrict__ C2) {
  __shared__ char lds[131072];
  const bool isq = (blockIdx.x < 192);
  const u16* A = isq ? A1 : A2;
  const u16* B = isq ? B1 : B2;
  u16*       C = isq ? C1 : C2;
  const int  N = isq ? 6144 : 8192;
  const int  K = isq ? 1536 : 512;
  const int wg = isq ? blockIdx.x : (blockIdx.x - 192);
  const int nwg = isq ? 192 : 256;
  const int nbx = isq ? 24 : 32;
  gemm8_body<1>(lds, A, B, C, N, K, wg, nwg, nbx);
}

// ---------- out-projection (f32 C) ----------
__global__ __launch_bounds__(512, 2) void gemm_out_k(const u16* __restrict__ A,
                                                     const u16* __restrict__ Bt,
                                                     float* __restrict__ C) {
  __shared__ char lds[131072];
  gemm8_body<0>(lds, A, Bt, C, 5120, 4096, blockIdx.x, 160, 20);
}

// ---------- RMSNorm q: sums 4 split-K slabs, then normalizes ----------
#define SLAB ((size_t)2048 * 2176)
__global__ __launch_bounds__(256) void norm_q_kernel(const float* __restrict__ x,
                                                     const float* __restrict__ w,
                                                     u16* __restrict__ y) {
  const int row = blockIdx.x, tid = threadIdx.x;
  const float* xr = x + (size_t)row * 2176;
  float v[6]; float ss = 0.f;
  #pragma unroll
  for (int i = 0; i < 6; ++i) {
    size_t o = tid + i * 256;
    v[i] = xr[o] + xr[o + SLAB] + xr[o + 2 * SLAB] + xr[o + 3 * SLAB];
    ss += v[i] * v[i];
  }
  __shared__ float sm[4];
  #pragma unroll
  for (int o = 32; o > 0; o >>= 1) ss += __shfl_down(ss, o, 64);
  if ((tid & 63) == 0) sm[tid >> 6] = ss;
  __syncthreads();
  float tot = sm[0] + sm[1] + sm[2] + sm[3];
  float rs = rsqrtf(tot * (1.f / 1536.f) + 1e-6f);
  #pragma unroll
  for (int i = 0; i < 6; ++i)
    y[(size_t)row * 1536 + tid + i * 256] = f2bf(v[i] * rs * w[tid + i * 256]);
}

// ---------- RMSNorm kv + RoPE(k): sums 4 slabs ----------
__global__ __launch_bounds__(256) void norm_kv_kernel(const float* __restrict__ kva,
                                                      const float* __restrict__ w,
                                                      const int* __restrict__ pos,
                                                      u16* __restrict__ comp,
                                                      u16* __restrict__ krope) {
  const int row = blockIdx.x, tid = threadIdx.x;
  const float* xr = kva + (size_t)row * 2176 + 1536;
  float v0 = xr[tid] + xr[tid + SLAB] + xr[tid + 2 * SLAB] + xr[tid + 3 * SLAB];
  size_t o1 = tid + 256;
  float v1 = xr[o1] + xr[o1 + SLAB] + xr[o1 + 2 * SLAB] + xr[o1 + 3 * SLAB];
  float ss = v0 * v0 + v1 * v1;
  __shared__ float sm[4];
  #pragma unroll
  for (int o = 32; o > 0; o >>= 1) ss += __shfl_down(ss, o, 64);
  if ((tid & 63) == 0) sm[tid >> 6] = ss;
  __syncthreads();
  float tot = sm[0] + sm[1] + sm[2] + sm[3];
  float rs = rsqrtf(tot * (1.f / 512.f) + 1e-6f);
  comp[(size_t)row * 512 + tid]       = f2bf(v0 * rs * w[tid]);
  comp[(size_t)row * 512 + tid + 256] = f2bf(v1 * rs * w[tid + 256]);
  if (tid < 32) {
    float p = (float)pos[row];
    float inv = powf(10000.0f, -(float)(2 * tid) * (1.0f / 64.0f));
    float ang = p * inv;
    float c = cosf(ang), s = sinf(ang);
    size_t e1 = 512 + 2 * tid, e2 = e1 + 1;
    float x1 = xr[e1] + xr[e1 + SLAB] + xr[e1 + 2 * SLAB] + xr[e1 + 3 * SLAB];
    float x2 = xr[e2] + xr[e2 + SLAB] + xr[e2 + 2 * SLAB] + xr[e2 + 3 * SLAB];
    krope[(size_t)row * 64 + 2 * tid]     = f2bf(x1 * c - x2 * s);
    krope[(size_t)row * 64 + 2 * tid + 1] = f2bf(x1 * s + x2 * c);
  }
}

// ---------- RoPE(q) + relayout q_all[h][t][192]  (q_big now bf16) ----------
__global__ __launch_bounds__(256) void rope_q_kernel(const u16* __restrict__ qb,
                                                     const int* __restrict__ pos,
                                                     u16* __restrict__ q_all) {
  const int t = blockIdx.x, tid = threadIdx.x;
  const u16* qr = qb + (size_t)t * 6144;
  const float p = (float)pos[t];
  // nope part: straight u32 copies (2048 pairs)
  for (int idx = tid; idx < 2048; idx += 256) {
    int h = idx >> 6, d2 = idx & 63;
    *(u32*)&q_all[((size_t)h * 2048 + t) * 192 + d2 * 2] = *(const u32*)&qr[h * 192 + d2 * 2];
  }
  for (int idx = tid; idx < 1024; idx += 256) {
    int h = idx >> 5, i = idx & 31;
    float inv = powf(10000.0f, -(float)(2 * i) * (1.0f / 64.0f));
    float ang = p * inv;
    float c = cosf(ang), s = sinf(ang);
    float x1 = b2f(qr[h * 192 + 128 + 2 * i]), x2 = b2f(qr[h * 192 + 128 + 2 * i + 1]);
    size_t ob = ((size_t)h * 2048 + t) * 192 + 128;
    q_all[ob + 2 * i]     = f2bf(x1 * c - x2 * s);
    q_all[ob + 2 * i + 1] = f2bf(x1 * s + x2 * c);
  }
}

// ---------- split kv -> k_all[h][s][200], v_t[h][d][2048]  (kv_big now bf16) ----------
__global__ __launch_bounds__(256) void kvsplit_kernel(const u16* __restrict__ kv,
                                                      const u16* __restrict__ krope,
                                                      u16* __restrict__ k_all,
                                                      u16* __restrict__ v_t) {
  const int h = blockIdx.x & 31, st = blockIdx.x >> 5, tid = threadIdx.x;
  const int s0 = st * 64;
  // k-nope: u32 copies
  for (int idx = tid; idx < 4096; idx += 256) {
    int s = idx >> 6, d2 = idx & 63;
    *(u32*)&k_all[((size_t)h * 2048 + s0 + s) * 200 + d2 * 2] =
        *(const u32*)&kv[(size_t)(s0 + s) * 8192 + h * 256 + d2 * 2];
  }
  // k-rope: u32 copies
  for (int idx = tid; idx < 2048; idx += 256) {
    int s = idx >> 5, j2 = idx & 31;
    *(u32*)&k_all[((size_t)h * 2048 + s0 + s) * 200 + 128 + j2 * 2] =
        *(const u32*)&krope[(size_t)(s0 + s) * 64 + j2 * 2];
  }
  __shared__ u16 vs[64][128];
  for (int idx = tid; idx < 4096; idx += 256) {
    int s = idx >> 6, d2 = idx & 63;
    *(u32*)&vs[s][d2 * 2] = *(const u32*)&kv[(size_t)(s0 + s) * 8192 + h * 256 + 128 + d2 * 2];
  }
  __syncthreads();
  const int d = tid >> 1, sh = (tid & 1) * 32;
  u16 tmp[32];
  #pragma unroll
  for (int i = 0; i < 32; ++i) tmp[i] = vs[sh + i][d];
  #pragma unroll
  for (int b = 0; b < 4; ++b) {
    u16x8 o;
    #pragma unroll
    for (int j = 0; j < 8; ++j) o[j] = tmp[b * 8 + j];
    *(u16x8*)(v_t + ((size_t)h * 128 + d) * 2048 + s0 + sh + b * 8) = o;
  }
}

// ---------- flash attention: 8 waves, 128q x 64s tiles, dbuf, swapped-QK ----------
#define SCL2 0.10412706f
#define THR2 11.5f
__global__ __launch_bounds__(512, 2) void attn_fwd(const u16* __restrict__ q_all,
                                                   const u16* __restrict__ k_all,
                                                   const u16* __restrict__ v_t,
                                                   u16* __restrict__ attnb) {
  __shared__ __align__(16) char lds[106496];
  const int tid = threadIdx.x;
  const int lane = tid & 63, wid = tid >> 6;
  const int lr = lane & 15, lg = lane >> 4;
  const int h = blockIdx.x & 31, bq = blockIdx.x >> 5;

  const char* kh = (const char*)(k_all + (size_t)h * 2048 * 200);
  const char* vh = (const char*)(v_t + (size_t)h * 128 * 2048);
  char* Pw = lds + 88064 + wid * 2304;

  const int nCalls = (wid < 3) ? 6 : 5;
  const char* gp[6]; int cofs[6]; int isK[6];
  #pragma unroll
  for (int ii = 0; ii < 6; ++ii) {
    int i = wid + (ii << 3);
    if (i < 43) {
      int c = (i << 6) + lane;
      cofs[ii] = c << 4;
      if (c < 1600) { gp[ii] = kh + ((size_t)c << 4); isK[ii] = 1; }
      else {
        int cv = c - 1600;
        int row = cv / 9, sub = cv - row * 9;
        gp[ii] = vh + ((size_t)row << 12) + ((sub < 8) ? (sub << 4) : 0);
        isK[ii] = 0;
      }
    } else { gp[ii] = kh; cofs[ii] = 0; isK[ii] = 1; }
  }

#define STAGE(s0_, bOff_)                                                       \
  { int _sk = (s0_) * 400, _sv = (s0_) * 2;                                     \
    _Pragma("unroll")                                                           \
    for (int ii = 0; ii < 6; ++ii)                                              \
      if (ii < nCalls)                                                          \
        gl16(gp[ii] + (isK[ii] ? _sk : _sv), lds + (bOff_) + cofs[ii]); }

#define WAITSTAGE                                                               \
  { if (wid < 3) { asm volatile("s_waitcnt vmcnt(6)" ::: "memory"); }           \
    else        { asm volatile("s_waitcnt vmcnt(5)" ::: "memory"); } }

  const int kRd = lr * 400 + lg * 16;
  const int vRd = lr * 144 + lg * 16;
  const int pRd = lr * 144 + lg * 16;
  const int pWr = lr * 144 + lg * 8;

  #pragma unroll
  for (int half = 0; half < 2; ++half) {
    const int qt = half ? (15 - bq) : bq;
    const int qb0 = qt << 7;
    const int nt = 2 * qt + 2;
    const int qlane = qb0 + wid * 16 + lr;
    const int qwmin = qb0 + wid * 16;

    bf16x8 qf[6];
    const u16* qptr = q_all + ((size_t)h * 2048 + qlane) * 192 + lg * 8;
    #pragma unroll
    for (int kf = 0; kf < 6; ++kf) qf[kf] = *(const bf16x8*)(qptr + kf * 32);

    f32x4 O[8] = {};
    float m = -1e30f, l = 0.f;

    STAGE(0, 0);
    for (int st = 0; st < nt; ++st) {
      const int s0 = st << 6;
      const int bOff = (st & 1) * 44032;
      if (st + 1 < nt) {
        STAGE((st + 1) << 6, ((st + 1) & 1) * 44032);
        WAITSTAGE;
      } else {
        WAITVM0;
      }
      BAR();

      const bool active = (s0 <= qwmin + 15);
      if (active) {
        const char* Kb = lds + bOff;
        const char* Vb = lds + bOff + 25600;

        f32x4 S[4];
        #pragma unroll
        for (int sb = 0; sb < 4; ++sb) {
          f32x4 a = {};
          #pragma unroll
          for (int kf = 0; kf < 6; ++kf) {
            bf16x8 kfr = *(const bf16x8*)(Kb + kRd + sb * 6400 + kf * 64);
            a = __builtin_amdgcn_mfma_f32_16x16x32_bf16(kfr, qf[kf], a, 0, 0, 0);
          }
          S[sb] = a;
        }

        if (s0 + 63 > qwmin) {
          const int kb0 = s0 + lg * 4;
          #pragma unroll
          for (int sb = 0; sb < 4; ++sb)
            #pragma unroll
            for (int r = 0; r < 4; ++r) {
              int k = kb0 + sb * 16 + r;
              S[sb][r] = (k > qlane) ? -1e30f : S[sb][r] * SCL2;
            }
        } else {
          #pragma unroll
          for (int sb = 0; sb < 4; ++sb)
            #pragma unroll
            for (int r = 0; r < 4; ++r) S[sb][r] *= SCL2;
        }

        float mx = S[0][0];
        #pragma unroll
        for (int sb = 0; sb < 4; ++sb)
          #pragma unroll
          for (int r = 0; r < 4; ++r) mx = fmaxf(mx, S[sb][r]);
        mx = fmaxf(mx, __shfl_xor(mx, 16, 64));
        mx = fmaxf(mx, __shfl_xor(mx, 32, 64));

        const bool skip = __all(mx <= m + THR2);
        float alpha = 1.f;
        if (!skip) { float mn = fmaxf(m, mx); alpha = exp2f(m - mn); m = mn; }

        float ps = 0.f;
        #pragma unroll
        for (int sb = 0; sb < 4; ++sb)
          #pragma unroll
          for (int r = 0; r < 4; ++r) {
            float pv = exp2f(S[sb][r] - m);
            S[sb][r] = pv;
            ps += pv;
          }
        ps += __shfl_xor(ps, 16, 64);
        ps += __shfl_xor(ps, 32, 64);
        l = l * alpha + ps;

        if (!skip) {
          float aO[4];
          #pragma unroll
          for (int r = 0; r < 4; ++r) aO[r] = __shfl(alpha, lg * 4 + r, 64);
          #pragma unroll
          for (int nb = 0; nb < 8; ++nb)
            #pragma unroll
            for (int r = 0; r < 4; ++r) O[nb][r] *= aO[r];
        }

        #pragma unroll
        for (int sb = 0; sb < 4; ++sb) {
          u32 p01, p23;
          asm("v_cvt_pk_bf16_f32 %0, %1, %2" : "=v"(p01) : "v"(S[sb][0]), "v"(S[sb][1]));
          asm("v_cvt_pk_bf16_f32 %0, %1, %2" : "=v"(p23) : "v"(S[sb][2]), "v"(S[sb][3]));
          *(uint2*)(Pw + pWr + sb * 32) = make_uint2(p01, p23);
        }

        #pragma unroll
        for (int k2 = 0; k2 < 2; ++k2) {
          bf16x8 pa = *(const bf16x8*)(Pw + pRd + k2 * 64);
          #pragma unroll
          for (int nb = 0; nb < 8; ++nb) {
            bf16x8 vf = *(const bf16x8*)(Vb + vRd + nb * 2304 + k2 * 64);
            O[nb] = __builtin_amdgcn_mfma_f32_16x16x32_bf16(pa, vf, O[nb], 0, 0, 0);
          }
        }
      }
      BAR();
    }

    float rv[4];
    #pragma unroll
    for (int r = 0; r < 4; ++r) rv[r] = 1.f / __shfl(l, lg * 4 + r, 64);
    #pragma unroll
    for (int nb = 0; nb < 8; ++nb) {
      const int col = h * 128 + nb * 16 + lr;
      #pragma unroll
      for (int r = 0; r < 4; ++r)
        attnb[(size_t)(qb0 + wid * 16 + lg * 4 + r) * 4096 + col] = f2bf(O[nb][r] * rv[r]);
    }
  }
#undef STAGE
#undef WAITSTAGE
}

// ---------- host ----------
extern "C" void kernel_launch(void* const* d_in, const int* in_sizes, int n_in,
                              void* d_out, int out_size, void* d_ws, size_t ws_size,
                              hipStream_t stream) {
  const int*   positions = (const int*)d_in[0];
  const float* hidden    = (const float*)d_in[1];
  const float* w_q_a     = (const float*)d_in[2];
  const float* q_a_norm  = (const float*)d_in[3];
  const float* w_q_b     = (const float*)d_in[4];
  const float* w_kv_a    = (const float*)d_in[5];
  const float* kv_a_norm = (const float*)d_in[6];
  const float* w_kv_b    = (const float*)d_in[7];
  const float* w_o       = (const float*)d_in[8];
  float* out = (float*)d_out;
  char*  ws  = (char*)d_ws;

  // layout (bytes), total 218,628,096:
  // [0)          hs_bf 20.97M  (dead after gemm_a)   -> wo_t reuses [0, 41.9M)
  // [20971520)   wqa_t 15.7M + wkva_t 6.55M          (dead after gemm_a)
  // [43253760)   wqb_t 18.87M
  // [62128128)   wkvb_t 8.39M
  // [70516736)   slabs 71.3M f32  -> later q_big16 / kv_big16 -> later attnb
  // [141819904)  q_c_n 6.29M | [148111360) comp 2.1M | [150208512) krope 0.26M
  // [150470656)  q_all 25.17M | [175636480) k_all 26.21M | [201850880) v_t 16.78M
  u16* hs_bf  = (u16*)(ws + 0);
  u16* wo_t   = (u16*)(ws + 0);                 // after gemm_a
  u16* wqa_t  = (u16*)(ws + 20971520);
  u16* wkva_t = (u16*)(ws + 20971520 + (size_t)1536 * 5120 * 2);
  u16* wqb_t  = (u16*)(ws + 43253760);
  u16* wkvb_t = (u16*)(ws + 62128128);
  float* slabs   = (float*)(ws + 70516736);
  u16* q_big16   = (u16*)(ws + 70516736);
  u16* kv_big16  = (u16*)(ws + 70516736 + 25165824);
  u16* attnb     = (u16*)(ws + 70516736);
  u16* q_c_n  = (u16*)(ws + 141819904);
  u16* comp   = (u16*)(ws + 148111360);
  u16* krope  = (u16*)(ws + 150208512);
  u16* q_all  = (u16*)(ws + 150470656);
  u16* k_all  = (u16*)(ws + 175636480);
  u16* v_t    = (u16*)(ws + 201850880);

  // stage-1 conversions
  cvt_f32_bf16<<<2048, 256, 0, stream>>>(hidden, hs_bf, (2048 * 5120) / 4);
  transpose_w<<<dim3(48, 160), 256, 0, stream>>>(w_q_a,  wqa_t,  5120, 1536, 1536);
  transpose_w<<<dim3(20, 160), 256, 0, stream>>>(w_kv_a, wkva_t, 5120, 576,  640);
  transpose_w<<<dim3(192, 48), 256, 0, stream>>>(w_q_b,  wqb_t,  1536, 6144, 6144);
  transpose_w<<<dim3(256, 16), 256, 0, stream>>>(w_kv_b, wkvb_t, 512,  8192, 8192);

  // merged LoRA-A GEMM, split-K=4 into slabs
  gemm_a<<<dim3(17, 16, 4), 256, 0, stream>>>(hs_bf, wqa_t, slabs, 2048, 2176, 5120, 20);

  // norms fuse the 4-slab reduction
  norm_q_kernel<<<2048, 256, 0, stream>>>(slabs, q_a_norm, q_c_n);
  norm_kv_kernel<<<2048, 256, 0, stream>>>(slabs, kv_a_norm, positions, comp, krope);

  // w_o transpose into the now-dead hs_bf/wqa region
  transpose_w<<<dim3(160, 128), 256, 0, stream>>>(w_o, wo_t, 4096, 5120, 5120);

  // fused q_b + kv_b (bf16 C)
  gemm_fused_b<<<448, 512, 0, stream>>>(q_c_n, wqb_t, q_big16, comp, wkvb_t, kv_big16);

  rope_q_kernel<<<2048, 256, 0, stream>>>(q_big16, positions, q_all);
  kvsplit_kernel<<<1024, 256, 0, stream>>>(kv_big16, krope, k_all, v_t);

  attn_fwd<<<256, 512, 0, stream>>>(q_all, k_all, v_t, attnb);

  gemm_out_k<<<160, 512, 0, stream>>>(attnb, wo_t, out);
}